// Round 8
// baseline (714.628 us; speedup 1.0000x reference)
//
#include <hip/hip_runtime.h>
#include <hip/hip_fp16.h>
#include <math.h>

#define F_IN 128
#define HID 64
#define NCLS 32
#define NEG 0.2f
#define NBKT 128          // nodes per bucket (dst >> 7)
#define BSH 7
#define BMSK 127
#define BCAPSH 12         // padded bucket capacity 4096 (mean fill ~2175)

using bf8 = __attribute__((ext_vector_type(8))) short;   // 8 bf16 (4 VGPRs)
using f4v = __attribute__((ext_vector_type(4))) float;   // MFMA acc
typedef _Float16 hv2 __attribute__((ext_vector_type(2)));

__device__ __forceinline__ void f4fma(float4& a, float s, const float4& w) {
    a.x = fmaf(s, w.x, a.x);
    a.y = fmaf(s, w.y, a.y);
    a.z = fmaf(s, w.z, a.z);
    a.w = fmaf(s, w.w, a.w);
}
// float -> bf16 (round to nearest even)
__device__ __forceinline__ unsigned short f2bf(float f) {
    unsigned u = __float_as_uint(f);
    return (unsigned short)((u + 0x7FFFu + ((u >> 16) & 1u)) >> 16);
}
// float -> f16 bits (RNE)
__device__ __forceinline__ unsigned short f2h(float f) {
    return __half_as_ushort(__float2half(f));
}
__device__ __forceinline__ float h2f(unsigned short u) {
    return __half2float(__ushort_as_half(u));
}
// packed f16 add + per-half abs (v_pk_add_f16 + v_and_b32)
__device__ __forceinline__ unsigned pkaddabs(unsigned a, unsigned b) {
    hv2 r = __builtin_bit_cast(hv2, a) + __builtin_bit_cast(hv2, b);
    return __builtin_bit_cast(unsigned, r) & 0x7FFF7FFFu;
}
// v_dot2_f32_f16
__device__ __forceinline__ float fdot2(unsigned a, unsigned b, float c) {
    return __builtin_amdgcn_fdot2(__builtin_bit_cast(hv2, a),
                                  __builtin_bit_cast(hv2, b), c, false);
}
__device__ __forceinline__ float h2lo(unsigned a) {
    return (float)__builtin_bit_cast(hv2, a).x;
}
__device__ __forceinline__ float h2hi(unsigned a) {
    return (float)__builtin_bit_cast(hv2, a).y;
}
// butterfly add via DPP (VALU pipe, no LDS/DS traffic)
// 0xB1 quad_perm xor1 | 0x4E quad_perm xor2 | 0x141 row_half_mirror (pairs 8-grps)
// 0x140 row_mirror (pairs 16-grp halves)    | 0x128 row_ror:8 (xor8 within 16)
template <int CTRL>
__device__ __forceinline__ float dpp_add(float v) {
    int t = __builtin_amdgcn_update_dpp(0, __float_as_int(v), CTRL, 0xf, 0xf, true);
    return v + __int_as_float(t);
}

// =====================  CSR build: padded-bucket counting sort  =====================
// Single scatter pass with global atomic cursors into fixed-capacity (4096) buckets;
// bucketHist pass eliminated.

__global__ __launch_bounds__(256) void scatterPad(const int* __restrict__ ei,
                                                  int Eorig, int Etot,
                                                  int* __restrict__ bucketSize,
                                                  int* __restrict__ pairs) {
    int i = blockIdx.x * 256 + threadIdx.x;
    if (i >= Etot) return;
    int src, dst;
    if (i < Eorig) { src = ei[i]; dst = ei[Eorig + i]; }
    else           { src = dst = i - Eorig; }
    int b = dst >> BSH;
    int off = atomicAdd(&bucketSize[b], 1);
    pairs[(b << BCAPSH) + off] = (src << BSH) | (dst & BMSK);
}

// scan over up to 1024 buckets (4 per thread); bucketSize holds counts
__global__ __launch_bounds__(256) void bucketScan(const int* __restrict__ bucketSize,
                                                  int* __restrict__ bucketStart,
                                                  int BK, int Etot) {
    __shared__ int sd[256];
    int t = threadIdx.x;
    int v[4]; int ts = 0;
#pragma unroll
    for (int k = 0; k < 4; k++) {
        v[k] = (4 * t + k < BK) ? bucketSize[4 * t + k] : 0;
        ts += v[k];
    }
    sd[t] = ts;
    __syncthreads();
    for (int off = 1; off < 256; off <<= 1) {
        int x = (t >= off) ? sd[t - off] : 0;
        __syncthreads();
        sd[t] += x;
        __syncthreads();
    }
    int excl = sd[t] - ts;
#pragma unroll
    for (int k = 0; k < 4; k++) {
        if (4 * t + k < BK) bucketStart[4 * t + k] = excl;
        excl += v[k];
    }
    if (t == 255) bucketStart[BK] = Etot;
}

__global__ __launch_bounds__(256) void bucketCSR(const int* __restrict__ pairs,
                                                 const int* __restrict__ bucketStart,
                                                 int* __restrict__ rowstart,
                                                 int* __restrict__ cnt,
                                                 int* __restrict__ srclist, int N) {
    __shared__ int c[256], cur[256];
    int t = threadIdx.x;
    int b = blockIdx.x;
    int lo = b * NBKT;
    int eb = bucketStart[b];
    int ecount = bucketStart[b + 1] - eb;
    const int* bp = pairs + ((size_t)b << BCAPSH);
    c[t] = 0;
    __syncthreads();
    for (int i = t; i < ecount; i += 256)
        atomicAdd(&c[bp[i] & BMSK], 1);
    __syncthreads();
    cur[t] = c[t];
    __syncthreads();
    for (int off = 1; off < 256; off <<= 1) {
        int x = (t >= off) ? cur[t - off] : 0;
        __syncthreads();
        cur[t] += x;
        __syncthreads();
    }
    int excl = cur[t] - c[t];
    int node = lo + t;
    if (t < NBKT && node < N) { rowstart[node] = eb + excl; cnt[node] = c[t]; }
    __syncthreads();
    cur[t] = excl;
    __syncthreads();
    for (int i = t; i < ecount; i += 256) {
        int v = bp[i];
        int pos = atomicAdd(&cur[v & BMSK], 1);
        srclist[eb + pos] = v >> BSH;
    }
}

// =====================  W1 frag prep + att f16 conversion  =====================
__global__ __launch_bounds__(256) void prepW(const float* __restrict__ Wl,
                                             const float* __restrict__ Wr,
                                             const float* __restrict__ att1,
                                             const float* __restrict__ att2,
                                             uint4* __restrict__ wfrag,
                                             unsigned short* __restrict__ att1h,
                                             unsigned short* __restrict__ att2h) {
    int e = blockIdx.x * 256 + threadIdx.x;
    if (e >= 2048) {
        int i = e - 2048;
        if (i < HID) att1h[i] = f2h(att1[i]);
        else if (i < HID + NCLS) att2h[i - HID] = f2h(att2[i - HID]);
        return;
    }
    int lane = e & 63;
    int kt = (e >> 6) & 3;
    int ct = (e >> 8) & 3;
    int mat = e >> 10;
    const float* W = mat ? Wr : Wl;
    int k0 = kt * 32 + (lane >> 4) * 8;
    int c = ct * 16 + (lane & 15);
    unsigned short h[8];
#pragma unroll
    for (int j = 0; j < 8; j++) h[j] = f2bf(W[(k0 + j) * HID + c]);
    wfrag[e] = *(uint4*)h;
}

// =====================  transform1: MFMA bf16  =====================
// xl and xr both emitted f16-packed. sl[node] = 0.6 * att . f16(xl[node,:]).
__global__ __launch_bounds__(256) void transform1(const float* __restrict__ x,
                                                  const uint4* __restrict__ wfrag,
                                                  const float* __restrict__ bl,
                                                  const float* __restrict__ br,
                                                  const float* __restrict__ att,
                                                  unsigned short* __restrict__ xlh,
                                                  unsigned short* __restrict__ xrh,
                                                  float* __restrict__ sl, int N) {
    __shared__ uint4 sw[2048];   // 32KB frag-ordered W (both matrices)
    int t = threadIdx.x;
#pragma unroll
    for (int j = 0; j < 8; j++) sw[t + j * 256] = wfrag[t + j * 256];
    __syncthreads();

    int w = t >> 6, lane = t & 63;
    int nb = blockIdx.x * 64 + w * 16;
    int m = lane & 15, quad = lane >> 4;

    // ---- A-frags: node = nb+m, k = kt*32 + quad*8 + j ----
    int arow = nb + m; if (arow >= N) arow = N - 1;
    const float* xrow = x + (size_t)arow * F_IN + quad * 8;
    bf8 afr[4];
#pragma unroll
    for (int kt = 0; kt < 4; kt++) {
        float4 lo = *(const float4*)(xrow + kt * 32);
        float4 hi = *(const float4*)(xrow + kt * 32 + 4);
        unsigned short hh[8];
        hh[0] = f2bf(lo.x); hh[1] = f2bf(lo.y); hh[2] = f2bf(lo.z); hh[3] = f2bf(lo.w);
        hh[4] = f2bf(hi.x); hh[5] = f2bf(hi.y); hh[6] = f2bf(hi.z); hh[7] = f2bf(hi.w);
        afr[kt] = *(bf8*)hh;
    }

    float am[4];
#pragma unroll
    for (int ct = 0; ct < 4; ct++) am[ct] = att[ct * 16 + m];
    float slp[4] = {0.f, 0.f, 0.f, 0.f};

    // ---- MFMA accumulate + store ----
#pragma unroll
    for (int mat = 0; mat < 2; mat++) {
        const float* bias = mat ? br : bl;
#pragma unroll
        for (int ct = 0; ct < 4; ct++) {
            f4v acc = {0.f, 0.f, 0.f, 0.f};
#pragma unroll
            for (int kt = 0; kt < 4; kt++) {
                bf8 bfr = *(bf8*)&sw[((mat * 4 + ct) * 4 + kt) * 64 + lane];
                acc = __builtin_amdgcn_mfma_f32_16x16x32_bf16(afr[kt], bfr, acc, 0, 0, 0);
            }
            int ch = ct * 16 + m;
            float bv = bias[ch];
#pragma unroll
            for (int reg = 0; reg < 4; reg++) {
                int node = nb + quad * 4 + reg;
                float o = acc[reg] + bv;
                if (mat) {
                    if (node < N) xrh[(size_t)node * HID + ch] = f2h(o);
                } else {
                    unsigned short hb = f2h(o);
                    slp[reg] = fmaf(am[ct], h2f(hb), slp[reg]);  // att . f16(xl)
                    if (node < N) xlh[(size_t)node * HID + ch] = hb;
                }
            }
        }
    }
    // reduce slp over the 16 m-lanes — all DPP (xor1, xor2, mirror8, mirror16)
#pragma unroll
    for (int reg = 0; reg < 4; reg++) {
        slp[reg] = dpp_add<0xB1>(slp[reg]);
        slp[reg] = dpp_add<0x4E>(slp[reg]);
        slp[reg] = dpp_add<0x141>(slp[reg]);
        slp[reg] = dpp_add<0x140>(slp[reg]);
    }
    if (m == 0) {
#pragma unroll
        for (int reg = 0; reg < 4; reg++) {
            int node = nb + quad * 4 + reg;
            if (node < N) sl[node] = 0.6f * slp[reg];
        }
    }
}

// transform2: fp32 math. xl + xr emitted f16-packed. ReLU fused.
// sl[node] = 0.6 * att . f16(xl[node,:]).
__global__ __launch_bounds__(256) void transform2(const float* __restrict__ h,
                                                  const float* __restrict__ Wl,
                                                  const float* __restrict__ bl,
                                                  const float* __restrict__ Wr,
                                                  const float* __restrict__ br,
                                                  const float* __restrict__ att,
                                                  unsigned short* __restrict__ xlh,
                                                  unsigned short* __restrict__ xrh,
                                                  float* __restrict__ sl, int N) {
    __shared__ float sWl[HID * NCLS];
    __shared__ float sWr[HID * NCLS];
    __shared__ float sx[128][68];
    int t = threadIdx.x;
    int nb = blockIdx.x * 128;

#pragma unroll
    for (int j = 0; j < 2; j++) {
        int f = t + j * 256;
        ((float4*)sWl)[f] = ((const float4*)Wl)[f];
        ((float4*)sWr)[f] = ((const float4*)Wr)[f];
    }
    int maxf = (N - nb) * 16;
#pragma unroll
    for (int j = 0; j < 8; j++) {
        int f = t + j * 256;
        int node = f >> 4, kc = f & 15;
        float4 v = {0.f, 0.f, 0.f, 0.f};
        if (f < maxf) v = ((const float4*)(h + (size_t)nb * HID))[f];
        v.x = fmaxf(v.x, 0.f);
        v.y = fmaxf(v.y, 0.f);
        v.z = fmaxf(v.z, 0.f);
        v.w = fmaxf(v.w, 0.f);
        *(float4*)&sx[node][kc * 4] = v;
    }
    __syncthreads();

    int c4 = (t & 7) * 4;
    int slot = t >> 3;
    float4 bl4 = *(const float4*)(bl + c4);
    float4 br4 = *(const float4*)(br + c4);
    float4 at4 = *(const float4*)(att + c4);
    float4 accl[4] = {bl4, bl4, bl4, bl4};
    float4 accr[4] = {br4, br4, br4, br4};

#pragma unroll 4
    for (int k4 = 0; k4 < HID / 4; k4++) {
        int k = k4 * 4;
        float4 wl0 = *(const float4*)&sWl[(k + 0) * NCLS + c4];
        float4 wl1 = *(const float4*)&sWl[(k + 1) * NCLS + c4];
        float4 wl2 = *(const float4*)&sWl[(k + 2) * NCLS + c4];
        float4 wl3 = *(const float4*)&sWl[(k + 3) * NCLS + c4];
        float4 wr0 = *(const float4*)&sWr[(k + 0) * NCLS + c4];
        float4 wr1 = *(const float4*)&sWr[(k + 1) * NCLS + c4];
        float4 wr2 = *(const float4*)&sWr[(k + 2) * NCLS + c4];
        float4 wr3 = *(const float4*)&sWr[(k + 3) * NCLS + c4];
#pragma unroll
        for (int j = 0; j < 4; j++) {
            float4 xv = *(const float4*)&sx[slot + j * 32][k];
            f4fma(accl[j], xv.x, wl0); f4fma(accr[j], xv.x, wr0);
            f4fma(accl[j], xv.y, wl1); f4fma(accr[j], xv.y, wr1);
            f4fma(accl[j], xv.z, wl2); f4fma(accr[j], xv.z, wr2);
            f4fma(accl[j], xv.w, wl3); f4fma(accr[j], xv.w, wr3);
        }
    }
#pragma unroll
    for (int j = 0; j < 4; j++) {
        ushort4 o;
        o.x = f2h(accl[j].x); o.y = f2h(accl[j].y);
        o.z = f2h(accl[j].z); o.w = f2h(accl[j].w);
        ushort4 orr;
        orr.x = f2h(accr[j].x); orr.y = f2h(accr[j].y);
        orr.z = f2h(accr[j].z); orr.w = f2h(accr[j].w);
        float slpj = fmaf(at4.x, h2f(o.x),
                     fmaf(at4.y, h2f(o.y),
                     fmaf(at4.z, h2f(o.z), at4.w * h2f(o.w))));
        slpj = dpp_add<0xB1>(slpj);
        slpj = dpp_add<0x4E>(slpj);
        slpj = dpp_add<0x141>(slpj);
        int g = nb + slot + j * 32;
        if (g < N) {
            *(ushort4*)(xlh + (size_t)g * NCLS + c4) = o;
            *(ushort4*)(xrh + (size_t)g * NCLS + c4) = orr;
            if ((t & 7) == 0) sl[g] = 0.6f * slpj;
        }
    }
}

// =====================  fused softmax aggregation v14 (4-buffer pipeline)  ======
// Gather-latency bound (R7 analysis): keep 3 row-gathers outstanding via 4 named
// buffers (rule #20: no runtime-indexed reg arrays). Prologue issues batches
// 0..2 — for deg<=24 that's the node's ENTIRE gather set in flight at once.
// logit (shifted): p = 0.4*sum_c att_c|u_c| + sl_src  (per-dst terms cancel).
#define LOADROW(VP, SRC)                                                  \
    {                                                                     \
        const unsigned short* rp = xlh + (unsigned)(SRC) * C + cb0;       \
        if (NH == 4) *(uint4*)(VP) = *(const uint4*)rp;                   \
        else         *(uint2*)(VP) = *(const uint2*)rp;                   \
    }

#define LOADB(VP, T, B)                                                   \
    {                                                                     \
        int e_ = (B) * 8 + slot;                                          \
        T = __shfl(slv, e_, 64);                                          \
        int s_ = __shfl(srcv, e_, 64);                                    \
        LOADROW(VP, s_)                                                   \
    }

#define COMPUTE(VP, T, B)                                                 \
    {                                                                     \
        float pa = 0.f;                                                   \
        _Pragma("unroll")                                                 \
        for (int j = 0; j < NH; j++)                                      \
            pa = fdot2(pkaddabs((VP)[j], xrp[j]), atp[j], pa);            \
        pa = dpp_add<0x128>(pa);                                          \
        pa += __shfl_xor(pa, 16, 64);                                     \
        pa += __shfl_xor(pa, 32, 64);                                     \
        float wgt = ((B) * 8 + slot < len) ? __expf(fmaf(0.4f, pa, (T)))  \
                                           : 0.f;                         \
        s += wgt;                                                         \
        _Pragma("unroll")                                                 \
        for (int j = 0; j < NH; j++) {                                    \
            acc[2 * j]     = fmaf(wgt, h2lo((VP)[j]), acc[2 * j]);        \
            acc[2 * j + 1] = fmaf(wgt, h2hi((VP)[j]), acc[2 * j + 1]);    \
        }                                                                 \
    }

template <int C>
__global__ __launch_bounds__(256) void fusedAggH(const unsigned short* __restrict__ xlh,
                                                 const unsigned short* __restrict__ xrh,
                                                 const unsigned short* __restrict__ atth,
                                                 const float* __restrict__ sl,
                                                 const int* __restrict__ rowstart,
                                                 const int* __restrict__ cnt,
                                                 const int* __restrict__ srclist,
                                                 const float* __restrict__ bias,
                                                 float* __restrict__ out, int N) {
    constexpr int CH = C / 8;      // channels per lane: 8 (C=64) / 4 (C=32)
    constexpr int NH = CH / 2;     // packed-pair regs
    int wid = threadIdx.x >> 6;
    int lane = threadIdx.x & 63;
    int n = blockIdx.x * 4 + wid;
    if (n >= N) return;

    int slot = lane & 7;           // edge within batch  (bits 0-2)
    int pos  = lane >> 3;          // channel group      (bits 3-5)
    int cb0  = pos * CH;

    unsigned xrp[NH], atp[NH];
    if (NH == 4) {
        *(uint4*)xrp = *(const uint4*)(xrh + (size_t)n * C + cb0);
        *(uint4*)atp = *(const uint4*)(atth + cb0);
    } else {
        *(uint2*)xrp = *(const uint2*)(xrh + (size_t)n * C + cb0);
        *(uint2*)atp = *(const uint2*)(atth + cb0);
    }

    int row = rowstart[n];
    int deg = cnt[n];

    float s = 0.f;
    float acc[CH];
#pragma unroll
    for (int c = 0; c < CH; c++) acc[c] = 0.f;

    for (int cb = 0; cb < deg; cb += 64) {
        int len = deg - cb; if (len > 64) len = 64;
        int len1 = len - 1;
        int li = lane < len ? lane : len1;
        int srcv = srclist[row + cb + li];
        float slv = sl[srcv];                 // per-chunk gather; shuffled per batch
        int nbatch = (len + 7) >> 3;

        unsigned vp0[NH], vp1[NH], vp2[NH], vp3[NH];
        float t0, t1, t2, t3;
        LOADB(vp0, t0, 0)
        if (nbatch > 1) LOADB(vp1, t1, 1)
        if (nbatch > 2) LOADB(vp2, t2, 2)

        int b = 0;
        while (true) {
            if (b + 3 < nbatch) LOADB(vp3, t3, b + 3)
            COMPUTE(vp0, t0, b)
            if (b + 1 >= nbatch) break;
            if (b + 4 < nbatch) LOADB(vp0, t0, b + 4)
            COMPUTE(vp1, t1, b + 1)
            if (b + 2 >= nbatch) break;
            if (b + 5 < nbatch) LOADB(vp1, t1, b + 5)
            COMPUTE(vp2, t2, b + 2)
            if (b + 3 >= nbatch) break;
            if (b + 6 < nbatch) LOADB(vp2, t2, b + 6)
            COMPUTE(vp3, t3, b + 3)
            if (b + 4 >= nbatch) break;
            b += 4;
        }
    }
    // cross-slot reduce over lane bits 0,1,2 — all DPP (VALU), zero DS ops
#pragma unroll
    for (int c = 0; c < CH; c++) {
        acc[c] = dpp_add<0xB1>(acc[c]);    // xor1
        acc[c] = dpp_add<0x4E>(acc[c]);    // xor2
        acc[c] = dpp_add<0x141>(acc[c]);   // half_mirror (completes 8-lane sum)
    }
    s = dpp_add<0xB1>(s);
    s = dpp_add<0x4E>(s);
    s = dpp_add<0x141>(s);

    if (slot == 0) {
        float inv = 1.f / (s + 1e-16f);
        float o8[CH];
        float bi[CH];
        if (NH == 4) {
            *(float4*)&bi[0] = *(const float4*)(bias + cb0);
            *(float4*)&bi[4] = *(const float4*)(bias + cb0 + 4);
        } else {
            *(float4*)&bi[0] = *(const float4*)(bias + cb0);
        }
#pragma unroll
        for (int c = 0; c < CH; c++) o8[c] = fmaf(acc[c], inv, bi[c]);
        if (NH == 4) {
            *(float4*)(out + (size_t)n * C + cb0)     = *(float4*)&o8[0];
            *(float4*)(out + (size_t)n * C + cb0 + 4) = *(float4*)&o8[4];
        } else {
            *(float4*)(out + (size_t)n * C + cb0) = *(float4*)&o8[0];
        }
    }
}

extern "C" void kernel_launch(void* const* d_in, const int* in_sizes, int n_in,
                              void* d_out, int out_size, void* d_ws, size_t ws_size,
                              hipStream_t stream) {
    const float* x     = (const float*)d_in[0];
    const int*   ei    = (const int*)d_in[1];
    const float* W1l   = (const float*)d_in[2];
    const float* b1l   = (const float*)d_in[3];
    const float* W1r   = (const float*)d_in[4];
    const float* b1r   = (const float*)d_in[5];
    const float* att1  = (const float*)d_in[6];
    const float* bias1 = (const float*)d_in[7];
    const float* W2l   = (const float*)d_in[8];
    const float* b2l   = (const float*)d_in[9];
    const float* W2r   = (const float*)d_in[10];
    const float* b2r   = (const float*)d_in[11];
    const float* att2  = (const float*)d_in[12];
    const float* bias2 = (const float*)d_in[13];
    float* out = (float*)d_out;

    int N     = in_sizes[0] / F_IN;   // 100000
    int Eorig = in_sizes[1] / 2;      // 1600000
    int Etot  = Eorig + N;
    int BK    = (N + NBKT - 1) / NBKT;   // 782 buckets (<=1024)

    char* p = (char*)d_ws;
    auto alloc = [&](size_t bytes) { void* r = (void*)p; p += (bytes + 255) & ~(size_t)255; return r; };
    unsigned short* xl1h = (unsigned short*)alloc((size_t)N * HID * 2);   // f16 table L1
    unsigned short* xr1h = (unsigned short*)alloc((size_t)N * HID * 2);   // f16 xr L1
    float* h       = (float*)alloc((size_t)N * HID * 4);
    unsigned short* xl2h = (unsigned short*)alloc((size_t)N * NCLS * 2);  // f16 table L2
    unsigned short* xr2h = (unsigned short*)alloc((size_t)N * NCLS * 2);  // f16 xr L2
    int*   cnt     = (int*)alloc((size_t)N * 4);
    int*   rowstart= (int*)alloc((size_t)N * 4);
    int*   srclist = (int*)alloc((size_t)Etot * 4);
    uint4* wfrag   = (uint4*)alloc(2048 * 16);   // frag-ordered bf16 W1
    float* sl1     = (float*)alloc((size_t)N * 4);   // 0.6*att1.xl1 per node
    float* sl2     = (float*)alloc((size_t)N * 4);   // 0.6*att2.xl2 per node
    unsigned short* att1h = (unsigned short*)alloc(HID * 2);
    unsigned short* att2h = (unsigned short*)alloc(NCLS * 2);
    int*   bucketSize   = (int*)alloc(1040 * 4);
    int*   bucketStart  = (int*)alloc(1040 * 4);
    // padded pairs (782<<12 ints = 12.8MB) aliased over h (25.6MB, dead during CSR build)
    int*   pairs   = (int*)h;

    // ---- CSR build (padded-bucket counting sort; hist pass eliminated) ----
    hipMemsetAsync(bucketSize, 0, 1040 * 4, stream);
    scatterPad<<<(Etot + 255) / 256, 256, 0, stream>>>(ei, Eorig, Etot, bucketSize, pairs);
    bucketScan<<<1, 256, 0, stream>>>(bucketSize, bucketStart, BK, Etot);
    bucketCSR<<<BK, 256, 0, stream>>>(pairs, bucketStart, rowstart, cnt, srclist, N);

    // ---- layer 1 ----
    prepW<<<9, 256, 0, stream>>>(W1l, W1r, att1, att2, wfrag, att1h, att2h);
    transform1<<<(N + 63) / 64, 256, 0, stream>>>(x, wfrag, b1l, b1r, att1, xl1h, xr1h, sl1, N);
    fusedAggH<HID><<<(N + 3) / 4, 256, 0, stream>>>(xl1h, xr1h, att1h, sl1, rowstart, cnt,
                                                    srclist, bias1, h, N);

    // ---- layer 2 ----
    transform2<<<(N + 127) / 128, 256, 0, stream>>>(h, W2l, b2l, W2r, b2r, att2, xl2h, xr2h, sl2, N);
    fusedAggH<NCLS><<<(N + 3) / 4, 256, 0, stream>>>(xl2h, xr2h, att2h, sl2, rowstart, cnt,
                                                     srclist, bias2, out, N);
}

// Round 9
// 316.803 us; speedup vs baseline: 2.2558x; 2.2558x over previous
//
#include <hip/hip_runtime.h>
#include <hip/hip_fp16.h>
#include <math.h>

#define F_IN 128
#define HID 64
#define NCLS 32
#define NEG 0.2f
#define NBKT 128          // nodes per bucket (dst >> 7)
#define BSH 7
#define BMSK 127
#define CHUNK 4096        // edges per block in bucket passes

using bf8 = __attribute__((ext_vector_type(8))) short;   // 8 bf16 (4 VGPRs)
using f4v = __attribute__((ext_vector_type(4))) float;   // MFMA acc
typedef _Float16 hv2 __attribute__((ext_vector_type(2)));

__device__ __forceinline__ void f4fma(float4& a, float s, const float4& w) {
    a.x = fmaf(s, w.x, a.x);
    a.y = fmaf(s, w.y, a.y);
    a.z = fmaf(s, w.z, a.z);
    a.w = fmaf(s, w.w, a.w);
}
// float -> bf16 (round to nearest even)
__device__ __forceinline__ unsigned short f2bf(float f) {
    unsigned u = __float_as_uint(f);
    return (unsigned short)((u + 0x7FFFu + ((u >> 16) & 1u)) >> 16);
}
// float -> f16 bits (RNE)
__device__ __forceinline__ unsigned short f2h(float f) {
    return __half_as_ushort(__float2half(f));
}
__device__ __forceinline__ float h2f(unsigned short u) {
    return __half2float(__ushort_as_half(u));
}
// packed f16 add + per-half abs (v_pk_add_f16 + v_and_b32)
__device__ __forceinline__ unsigned pkaddabs(unsigned a, unsigned b) {
    hv2 r = __builtin_bit_cast(hv2, a) + __builtin_bit_cast(hv2, b);
    return __builtin_bit_cast(unsigned, r) & 0x7FFF7FFFu;
}
// v_dot2_f32_f16
__device__ __forceinline__ float fdot2(unsigned a, unsigned b, float c) {
    return __builtin_amdgcn_fdot2(__builtin_bit_cast(hv2, a),
                                  __builtin_bit_cast(hv2, b), c, false);
}
__device__ __forceinline__ float h2lo(unsigned a) {
    return (float)__builtin_bit_cast(hv2, a).x;
}
__device__ __forceinline__ float h2hi(unsigned a) {
    return (float)__builtin_bit_cast(hv2, a).y;
}
// butterfly add via DPP (VALU pipe, no LDS/DS traffic)
// 0xB1 quad_perm xor1 | 0x4E quad_perm xor2 | 0x141 row_half_mirror (pairs 8-grps)
// 0x140 row_mirror (pairs 16-grp halves)    | 0x128 row_ror:8 (xor8 within 16)
template <int CTRL>
__device__ __forceinline__ float dpp_add(float v) {
    int t = __builtin_amdgcn_update_dpp(0, __float_as_int(v), CTRL, 0xf, 0xf, true);
    return v + __int_as_float(t);
}

// =====================  CSR build: bucketed counting sort (R7 pipeline)  ========
// LDS-staged histograms + per-block base offsets: no same-address global atomic
// storms, same-bucket pair writes contiguous (R8's global-cursor scatter was 437us
// from 2200-deep atomic serialization + 10x write amplification).

__global__ __launch_bounds__(256) void bucketHist(const int* __restrict__ ei,
                                                  int Eorig, int Etot,
                                                  int* __restrict__ bucketSize, int BK) {
    __shared__ int h[1024];
    int t = threadIdx.x;
    for (int j = t; j < BK; j += 256) h[j] = 0;
    __syncthreads();
    int base = blockIdx.x * CHUNK;
    int end = base + CHUNK < Etot ? base + CHUNK : Etot;
    for (int i = base + t; i < end; i += 256) {
        int dst = i < Eorig ? ei[Eorig + i] : i - Eorig;
        atomicAdd(&h[dst >> BSH], 1);
    }
    __syncthreads();
    for (int j = t; j < BK; j += 256)
        if (h[j]) atomicAdd(&bucketSize[j], h[j]);
}

// scan over up to 1024 buckets (4 per thread)
__global__ __launch_bounds__(256) void bucketScan(const int* __restrict__ bucketSize,
                                                  int* __restrict__ bucketStart,
                                                  int* __restrict__ bucketCursor,
                                                  int BK, int Etot) {
    __shared__ int sd[256];
    int t = threadIdx.x;
    int v[4]; int ts = 0;
#pragma unroll
    for (int k = 0; k < 4; k++) {
        v[k] = (4 * t + k < BK) ? bucketSize[4 * t + k] : 0;
        ts += v[k];
    }
    sd[t] = ts;
    __syncthreads();
    for (int off = 1; off < 256; off <<= 1) {
        int x = (t >= off) ? sd[t - off] : 0;
        __syncthreads();
        sd[t] += x;
        __syncthreads();
    }
    int excl = sd[t] - ts;
#pragma unroll
    for (int k = 0; k < 4; k++) {
        if (4 * t + k < BK) { bucketStart[4 * t + k] = excl; bucketCursor[4 * t + k] = excl; }
        excl += v[k];
    }
    if (t == 255) bucketStart[BK] = Etot;
}

// pairs packed: (src << 7) | (dst & 127)   — src < 2^17, fits in int
__global__ __launch_bounds__(256) void bucketScatter(const int* __restrict__ ei,
                                                     int Eorig, int Etot,
                                                     int* __restrict__ bucketCursor,
                                                     int* __restrict__ pairs, int BK) {
    __shared__ int h[1024], lbase[1024], hcur[1024];
    int t = threadIdx.x;
    for (int j = t; j < BK; j += 256) { h[j] = 0; hcur[j] = 0; }
    __syncthreads();
    int base = blockIdx.x * CHUNK;
    int end = base + CHUNK < Etot ? base + CHUNK : Etot;
    for (int i = base + t; i < end; i += 256) {
        int dst = i < Eorig ? ei[Eorig + i] : i - Eorig;
        atomicAdd(&h[dst >> BSH], 1);
    }
    __syncthreads();
    for (int j = t; j < BK; j += 256)
        lbase[j] = h[j] ? atomicAdd(&bucketCursor[j], h[j]) : 0;
    __syncthreads();
    for (int i = base + t; i < end; i += 256) {
        int src, dst;
        if (i < Eorig) { src = ei[i]; dst = ei[Eorig + i]; }
        else           { src = dst = i - Eorig; }
        int b = dst >> BSH;
        int off = atomicAdd(&hcur[b], 1);
        pairs[lbase[b] + off] = (src << BSH) | (dst & BMSK);
    }
}

__global__ __launch_bounds__(256) void bucketCSR(const int* __restrict__ pairs,
                                                 const int* __restrict__ bucketStart,
                                                 int* __restrict__ rowstart,
                                                 int* __restrict__ cnt,
                                                 int* __restrict__ srclist, int N) {
    __shared__ int c[256], cur[256];
    int t = threadIdx.x;
    int b = blockIdx.x;
    int lo = b * NBKT;
    int eb = bucketStart[b], ee = bucketStart[b + 1];
    c[t] = 0;
    __syncthreads();
    for (int i = eb + t; i < ee; i += 256)
        atomicAdd(&c[pairs[i] & BMSK], 1);
    __syncthreads();
    cur[t] = c[t];
    __syncthreads();
    for (int off = 1; off < 256; off <<= 1) {
        int x = (t >= off) ? cur[t - off] : 0;
        __syncthreads();
        cur[t] += x;
        __syncthreads();
    }
    int excl = cur[t] - c[t];
    int node = lo + t;
    if (t < NBKT && node < N) { rowstart[node] = eb + excl; cnt[node] = c[t]; }
    __syncthreads();
    cur[t] = excl;
    __syncthreads();
    for (int i = eb + t; i < ee; i += 256) {
        int v = pairs[i];
        int pos = atomicAdd(&cur[v & BMSK], 1);
        srclist[eb + pos] = v >> BSH;
    }
}

// =====================  W1 frag prep + att f16 conversion  =====================
__global__ __launch_bounds__(256) void prepW(const float* __restrict__ Wl,
                                             const float* __restrict__ Wr,
                                             const float* __restrict__ att1,
                                             const float* __restrict__ att2,
                                             uint4* __restrict__ wfrag,
                                             unsigned short* __restrict__ att1h,
                                             unsigned short* __restrict__ att2h) {
    int e = blockIdx.x * 256 + threadIdx.x;
    if (e >= 2048) {
        int i = e - 2048;
        if (i < HID) att1h[i] = f2h(att1[i]);
        else if (i < HID + NCLS) att2h[i - HID] = f2h(att2[i - HID]);
        return;
    }
    int lane = e & 63;
    int kt = (e >> 6) & 3;
    int ct = (e >> 8) & 3;
    int mat = e >> 10;
    const float* W = mat ? Wr : Wl;
    int k0 = kt * 32 + (lane >> 4) * 8;
    int c = ct * 16 + (lane & 15);
    unsigned short h[8];
#pragma unroll
    for (int j = 0; j < 8; j++) h[j] = f2bf(W[(k0 + j) * HID + c]);
    wfrag[e] = *(uint4*)h;
}

// =====================  transform1: MFMA bf16  =====================
// xl and xr both emitted f16-packed. sl[node] = 0.6 * att . f16(xl[node,:]).
__global__ __launch_bounds__(256) void transform1(const float* __restrict__ x,
                                                  const uint4* __restrict__ wfrag,
                                                  const float* __restrict__ bl,
                                                  const float* __restrict__ br,
                                                  const float* __restrict__ att,
                                                  unsigned short* __restrict__ xlh,
                                                  unsigned short* __restrict__ xrh,
                                                  float* __restrict__ sl, int N) {
    __shared__ uint4 sw[2048];   // 32KB frag-ordered W (both matrices)
    int t = threadIdx.x;
#pragma unroll
    for (int j = 0; j < 8; j++) sw[t + j * 256] = wfrag[t + j * 256];
    __syncthreads();

    int w = t >> 6, lane = t & 63;
    int nb = blockIdx.x * 64 + w * 16;
    int m = lane & 15, quad = lane >> 4;

    // ---- A-frags: node = nb+m, k = kt*32 + quad*8 + j ----
    int arow = nb + m; if (arow >= N) arow = N - 1;
    const float* xrow = x + (size_t)arow * F_IN + quad * 8;
    bf8 afr[4];
#pragma unroll
    for (int kt = 0; kt < 4; kt++) {
        float4 lo = *(const float4*)(xrow + kt * 32);
        float4 hi = *(const float4*)(xrow + kt * 32 + 4);
        unsigned short hh[8];
        hh[0] = f2bf(lo.x); hh[1] = f2bf(lo.y); hh[2] = f2bf(lo.z); hh[3] = f2bf(lo.w);
        hh[4] = f2bf(hi.x); hh[5] = f2bf(hi.y); hh[6] = f2bf(hi.z); hh[7] = f2bf(hi.w);
        afr[kt] = *(bf8*)hh;
    }

    float am[4];
#pragma unroll
    for (int ct = 0; ct < 4; ct++) am[ct] = att[ct * 16 + m];
    float slp[4] = {0.f, 0.f, 0.f, 0.f};

    // ---- MFMA accumulate + store ----
#pragma unroll
    for (int mat = 0; mat < 2; mat++) {
        const float* bias = mat ? br : bl;
#pragma unroll
        for (int ct = 0; ct < 4; ct++) {
            f4v acc = {0.f, 0.f, 0.f, 0.f};
#pragma unroll
            for (int kt = 0; kt < 4; kt++) {
                bf8 bfr = *(bf8*)&sw[((mat * 4 + ct) * 4 + kt) * 64 + lane];
                acc = __builtin_amdgcn_mfma_f32_16x16x32_bf16(afr[kt], bfr, acc, 0, 0, 0);
            }
            int ch = ct * 16 + m;
            float bv = bias[ch];
#pragma unroll
            for (int reg = 0; reg < 4; reg++) {
                int node = nb + quad * 4 + reg;
                float o = acc[reg] + bv;
                if (mat) {
                    if (node < N) xrh[(size_t)node * HID + ch] = f2h(o);
                } else {
                    unsigned short hb = f2h(o);
                    slp[reg] = fmaf(am[ct], h2f(hb), slp[reg]);  // att . f16(xl)
                    if (node < N) xlh[(size_t)node * HID + ch] = hb;
                }
            }
        }
    }
    // reduce slp over the 16 m-lanes — all DPP (xor1, xor2, mirror8, mirror16)
#pragma unroll
    for (int reg = 0; reg < 4; reg++) {
        slp[reg] = dpp_add<0xB1>(slp[reg]);
        slp[reg] = dpp_add<0x4E>(slp[reg]);
        slp[reg] = dpp_add<0x141>(slp[reg]);
        slp[reg] = dpp_add<0x140>(slp[reg]);
    }
    if (m == 0) {
#pragma unroll
        for (int reg = 0; reg < 4; reg++) {
            int node = nb + quad * 4 + reg;
            if (node < N) sl[node] = 0.6f * slp[reg];
        }
    }
}

// transform2: fp32 math. xl + xr emitted f16-packed. ReLU fused.
// sl[node] = 0.6 * att . f16(xl[node,:]).
__global__ __launch_bounds__(256) void transform2(const float* __restrict__ h,
                                                  const float* __restrict__ Wl,
                                                  const float* __restrict__ bl,
                                                  const float* __restrict__ Wr,
                                                  const float* __restrict__ br,
                                                  const float* __restrict__ att,
                                                  unsigned short* __restrict__ xlh,
                                                  unsigned short* __restrict__ xrh,
                                                  float* __restrict__ sl, int N) {
    __shared__ float sWl[HID * NCLS];
    __shared__ float sWr[HID * NCLS];
    __shared__ float sx[128][68];
    int t = threadIdx.x;
    int nb = blockIdx.x * 128;

#pragma unroll
    for (int j = 0; j < 2; j++) {
        int f = t + j * 256;
        ((float4*)sWl)[f] = ((const float4*)Wl)[f];
        ((float4*)sWr)[f] = ((const float4*)Wr)[f];
    }
    int maxf = (N - nb) * 16;
#pragma unroll
    for (int j = 0; j < 8; j++) {
        int f = t + j * 256;
        int node = f >> 4, kc = f & 15;
        float4 v = {0.f, 0.f, 0.f, 0.f};
        if (f < maxf) v = ((const float4*)(h + (size_t)nb * HID))[f];
        v.x = fmaxf(v.x, 0.f);
        v.y = fmaxf(v.y, 0.f);
        v.z = fmaxf(v.z, 0.f);
        v.w = fmaxf(v.w, 0.f);
        *(float4*)&sx[node][kc * 4] = v;
    }
    __syncthreads();

    int c4 = (t & 7) * 4;
    int slot = t >> 3;
    float4 bl4 = *(const float4*)(bl + c4);
    float4 br4 = *(const float4*)(br + c4);
    float4 at4 = *(const float4*)(att + c4);
    float4 accl[4] = {bl4, bl4, bl4, bl4};
    float4 accr[4] = {br4, br4, br4, br4};

#pragma unroll 4
    for (int k4 = 0; k4 < HID / 4; k4++) {
        int k = k4 * 4;
        float4 wl0 = *(const float4*)&sWl[(k + 0) * NCLS + c4];
        float4 wl1 = *(const float4*)&sWl[(k + 1) * NCLS + c4];
        float4 wl2 = *(const float4*)&sWl[(k + 2) * NCLS + c4];
        float4 wl3 = *(const float4*)&sWl[(k + 3) * NCLS + c4];
        float4 wr0 = *(const float4*)&sWr[(k + 0) * NCLS + c4];
        float4 wr1 = *(const float4*)&sWr[(k + 1) * NCLS + c4];
        float4 wr2 = *(const float4*)&sWr[(k + 2) * NCLS + c4];
        float4 wr3 = *(const float4*)&sWr[(k + 3) * NCLS + c4];
#pragma unroll
        for (int j = 0; j < 4; j++) {
            float4 xv = *(const float4*)&sx[slot + j * 32][k];
            f4fma(accl[j], xv.x, wl0); f4fma(accr[j], xv.x, wr0);
            f4fma(accl[j], xv.y, wl1); f4fma(accr[j], xv.y, wr1);
            f4fma(accl[j], xv.z, wl2); f4fma(accr[j], xv.z, wr2);
            f4fma(accl[j], xv.w, wl3); f4fma(accr[j], xv.w, wr3);
        }
    }
#pragma unroll
    for (int j = 0; j < 4; j++) {
        ushort4 o;
        o.x = f2h(accl[j].x); o.y = f2h(accl[j].y);
        o.z = f2h(accl[j].z); o.w = f2h(accl[j].w);
        ushort4 orr;
        orr.x = f2h(accr[j].x); orr.y = f2h(accr[j].y);
        orr.z = f2h(accr[j].z); orr.w = f2h(accr[j].w);
        float slpj = fmaf(at4.x, h2f(o.x),
                     fmaf(at4.y, h2f(o.y),
                     fmaf(at4.z, h2f(o.z), at4.w * h2f(o.w))));
        slpj = dpp_add<0xB1>(slpj);
        slpj = dpp_add<0x4E>(slpj);
        slpj = dpp_add<0x141>(slpj);
        int g = nb + slot + j * 32;
        if (g < N) {
            *(ushort4*)(xlh + (size_t)g * NCLS + c4) = o;
            *(ushort4*)(xrh + (size_t)g * NCLS + c4) = orr;
            if ((t & 7) == 0) sl[g] = 0.6f * slpj;
        }
    }
}

// =====================  fused softmax aggregation v14 (4-buffer pipeline)  ======
// Gather-latency bound: keep 3 row-gathers outstanding via 4 named buffers.
// logit (shifted): p = 0.4*sum_c att_c|u_c| + sl_src  (per-dst terms cancel).
#define LOADROW(VP, SRC)                                                  \
    {                                                                     \
        const unsigned short* rp = xlh + (unsigned)(SRC) * C + cb0;       \
        if (NH == 4) *(uint4*)(VP) = *(const uint4*)rp;                   \
        else         *(uint2*)(VP) = *(const uint2*)rp;                   \
    }

#define LOADB(VP, T, B)                                                   \
    {                                                                     \
        int e_ = (B) * 8 + slot;                                          \
        T = __shfl(slv, e_, 64);                                          \
        int s_ = __shfl(srcv, e_, 64);                                    \
        LOADROW(VP, s_)                                                   \
    }

#define COMPUTE(VP, T, B)                                                 \
    {                                                                     \
        float pa = 0.f;                                                   \
        _Pragma("unroll")                                                 \
        for (int j = 0; j < NH; j++)                                      \
            pa = fdot2(pkaddabs((VP)[j], xrp[j]), atp[j], pa);            \
        pa = dpp_add<0x128>(pa);                                          \
        pa += __shfl_xor(pa, 16, 64);                                     \
        pa += __shfl_xor(pa, 32, 64);                                     \
        float wgt = ((B) * 8 + slot < len) ? __expf(fmaf(0.4f, pa, (T)))  \
                                           : 0.f;                         \
        s += wgt;                                                         \
        _Pragma("unroll")                                                 \
        for (int j = 0; j < NH; j++) {                                    \
            acc[2 * j]     = fmaf(wgt, h2lo((VP)[j]), acc[2 * j]);        \
            acc[2 * j + 1] = fmaf(wgt, h2hi((VP)[j]), acc[2 * j + 1]);    \
        }                                                                 \
    }

template <int C>
__global__ __launch_bounds__(256) void fusedAggH(const unsigned short* __restrict__ xlh,
                                                 const unsigned short* __restrict__ xrh,
                                                 const unsigned short* __restrict__ atth,
                                                 const float* __restrict__ sl,
                                                 const int* __restrict__ rowstart,
                                                 const int* __restrict__ cnt,
                                                 const int* __restrict__ srclist,
                                                 const float* __restrict__ bias,
                                                 float* __restrict__ out, int N) {
    constexpr int CH = C / 8;      // channels per lane: 8 (C=64) / 4 (C=32)
    constexpr int NH = CH / 2;     // packed-pair regs
    int wid = threadIdx.x >> 6;
    int lane = threadIdx.x & 63;
    int n = blockIdx.x * 4 + wid;
    if (n >= N) return;

    int slot = lane & 7;           // edge within batch  (bits 0-2)
    int pos  = lane >> 3;          // channel group      (bits 3-5)
    int cb0  = pos * CH;

    unsigned xrp[NH], atp[NH];
    if (NH == 4) {
        *(uint4*)xrp = *(const uint4*)(xrh + (size_t)n * C + cb0);
        *(uint4*)atp = *(const uint4*)(atth + cb0);
    } else {
        *(uint2*)xrp = *(const uint2*)(xrh + (size_t)n * C + cb0);
        *(uint2*)atp = *(const uint2*)(atth + cb0);
    }

    int row = rowstart[n];
    int deg = cnt[n];

    float s = 0.f;
    float acc[CH];
#pragma unroll
    for (int c = 0; c < CH; c++) acc[c] = 0.f;

    for (int cb = 0; cb < deg; cb += 64) {
        int len = deg - cb; if (len > 64) len = 64;
        int len1 = len - 1;
        int li = lane < len ? lane : len1;
        int srcv = srclist[row + cb + li];
        float slv = sl[srcv];                 // per-chunk gather; shuffled per batch
        int nbatch = (len + 7) >> 3;

        unsigned vp0[NH], vp1[NH], vp2[NH], vp3[NH];
        float t0, t1, t2, t3;
        LOADB(vp0, t0, 0)
        if (nbatch > 1) LOADB(vp1, t1, 1)
        if (nbatch > 2) LOADB(vp2, t2, 2)

        int b = 0;
        while (true) {
            if (b + 3 < nbatch) LOADB(vp3, t3, b + 3)
            COMPUTE(vp0, t0, b)
            if (b + 1 >= nbatch) break;
            if (b + 4 < nbatch) LOADB(vp0, t0, b + 4)
            COMPUTE(vp1, t1, b + 1)
            if (b + 2 >= nbatch) break;
            if (b + 5 < nbatch) LOADB(vp1, t1, b + 5)
            COMPUTE(vp2, t2, b + 2)
            if (b + 3 >= nbatch) break;
            if (b + 6 < nbatch) LOADB(vp2, t2, b + 6)
            COMPUTE(vp3, t3, b + 3)
            if (b + 4 >= nbatch) break;
            b += 4;
        }
    }
    // cross-slot reduce over lane bits 0,1,2 — all DPP (VALU), zero DS ops
#pragma unroll
    for (int c = 0; c < CH; c++) {
        acc[c] = dpp_add<0xB1>(acc[c]);    // xor1
        acc[c] = dpp_add<0x4E>(acc[c]);    // xor2
        acc[c] = dpp_add<0x141>(acc[c]);   // half_mirror (completes 8-lane sum)
    }
    s = dpp_add<0xB1>(s);
    s = dpp_add<0x4E>(s);
    s = dpp_add<0x141>(s);

    if (slot == 0) {
        float inv = 1.f / (s + 1e-16f);
        float o8[CH];
        float bi[CH];
        if (NH == 4) {
            *(float4*)&bi[0] = *(const float4*)(bias + cb0);
            *(float4*)&bi[4] = *(const float4*)(bias + cb0 + 4);
        } else {
            *(float4*)&bi[0] = *(const float4*)(bias + cb0);
        }
#pragma unroll
        for (int c = 0; c < CH; c++) o8[c] = fmaf(acc[c], inv, bi[c]);
        if (NH == 4) {
            *(float4*)(out + (size_t)n * C + cb0)     = *(float4*)&o8[0];
            *(float4*)(out + (size_t)n * C + cb0 + 4) = *(float4*)&o8[4];
        } else {
            *(float4*)(out + (size_t)n * C + cb0) = *(float4*)&o8[0];
        }
    }
}

extern "C" void kernel_launch(void* const* d_in, const int* in_sizes, int n_in,
                              void* d_out, int out_size, void* d_ws, size_t ws_size,
                              hipStream_t stream) {
    const float* x     = (const float*)d_in[0];
    const int*   ei    = (const int*)d_in[1];
    const float* W1l   = (const float*)d_in[2];
    const float* b1l   = (const float*)d_in[3];
    const float* W1r   = (const float*)d_in[4];
    const float* b1r   = (const float*)d_in[5];
    const float* att1  = (const float*)d_in[6];
    const float* bias1 = (const float*)d_in[7];
    const float* W2l   = (const float*)d_in[8];
    const float* b2l   = (const float*)d_in[9];
    const float* W2r   = (const float*)d_in[10];
    const float* b2r   = (const float*)d_in[11];
    const float* att2  = (const float*)d_in[12];
    const float* bias2 = (const float*)d_in[13];
    float* out = (float*)d_out;

    int N     = in_sizes[0] / F_IN;   // 100000
    int Eorig = in_sizes[1] / 2;      // 1600000
    int Etot  = Eorig + N;
    int BK    = (N + NBKT - 1) / NBKT;   // 782 buckets (<=1024)

    char* p = (char*)d_ws;
    auto alloc = [&](size_t bytes) { void* r = (void*)p; p += (bytes + 255) & ~(size_t)255; return r; };
    unsigned short* xl1h = (unsigned short*)alloc((size_t)N * HID * 2);   // f16 table L1
    unsigned short* xr1h = (unsigned short*)alloc((size_t)N * HID * 2);   // f16 xr L1
    float* h       = (float*)alloc((size_t)N * HID * 4);
    unsigned short* xl2h = (unsigned short*)alloc((size_t)N * NCLS * 2);  // f16 table L2
    unsigned short* xr2h = (unsigned short*)alloc((size_t)N * NCLS * 2);  // f16 xr L2
    int*   cnt     = (int*)alloc((size_t)N * 4);
    int*   rowstart= (int*)alloc((size_t)N * 4);
    int*   srclist = (int*)alloc((size_t)Etot * 4);
    uint4* wfrag   = (uint4*)alloc(2048 * 16);   // frag-ordered bf16 W1
    float* sl1     = (float*)alloc((size_t)N * 4);   // 0.6*att1.xl1 per node
    float* sl2     = (float*)alloc((size_t)N * 4);   // 0.6*att2.xl2 per node
    unsigned short* att1h = (unsigned short*)alloc(HID * 2);
    unsigned short* att2h = (unsigned short*)alloc(NCLS * 2);
    int*   bucketSize   = (int*)alloc(1040 * 4);
    int*   bucketStart  = (int*)alloc(1040 * 4);
    int*   bucketCursor = (int*)alloc(1040 * 4);
    // packed pairs (6.8MB) aliased over h (25.6MB, dead during CSR build)
    int*   pairs   = (int*)h;

    int nChunks = (Etot + CHUNK - 1) / CHUNK;

    // ---- CSR build (bucketed counting sort) ----
    hipMemsetAsync(bucketSize, 0, 1040 * 4, stream);
    bucketHist<<<nChunks, 256, 0, stream>>>(ei, Eorig, Etot, bucketSize, BK);
    bucketScan<<<1, 256, 0, stream>>>(bucketSize, bucketStart, bucketCursor, BK, Etot);
    bucketScatter<<<nChunks, 256, 0, stream>>>(ei, Eorig, Etot, bucketCursor, pairs, BK);
    bucketCSR<<<BK, 256, 0, stream>>>(pairs, bucketStart, rowstart, cnt, srclist, N);

    // ---- layer 1 ----
    prepW<<<9, 256, 0, stream>>>(W1l, W1r, att1, att2, wfrag, att1h, att2h);
    transform1<<<(N + 63) / 64, 256, 0, stream>>>(x, wfrag, b1l, b1r, att1, xl1h, xr1h, sl1, N);
    fusedAggH<HID><<<(N + 3) / 4, 256, 0, stream>>>(xl1h, xr1h, att1h, sl1, rowstart, cnt,
                                                    srclist, bias1, h, N);

    // ---- layer 2 ----
    transform2<<<(N + 127) / 128, 256, 0, stream>>>(h, W2l, b2l, W2r, b2r, att2, xl2h, xr2h, sl2, N);
    fusedAggH<NCLS><<<(N + 3) / 4, 256, 0, stream>>>(xl2h, xr2h, att2h, sl2, rowstart, cnt,
                                                     srclist, bias2, out, N);
}

// Round 10
// 301.996 us; speedup vs baseline: 2.3664x; 1.0490x over previous
//
#include <hip/hip_runtime.h>
#include <hip/hip_fp16.h>
#include <math.h>

#define F_IN 128
#define HID 64
#define NCLS 32
#define NEG 0.2f
#define NBKT 128          // nodes per bucket (dst >> 7)
#define BSH 7
#define BMSK 127
#define CHUNK 4096        // edges per block in bucket passes

using bf8 = __attribute__((ext_vector_type(8))) short;   // 8 bf16 (4 VGPRs)
using f4v = __attribute__((ext_vector_type(4))) float;   // MFMA acc
typedef _Float16 hv2 __attribute__((ext_vector_type(2)));

__device__ __forceinline__ void f4fma(float4& a, float s, const float4& w) {
    a.x = fmaf(s, w.x, a.x);
    a.y = fmaf(s, w.y, a.y);
    a.z = fmaf(s, w.z, a.z);
    a.w = fmaf(s, w.w, a.w);
}
// float -> bf16 (round to nearest even)
__device__ __forceinline__ unsigned short f2bf(float f) {
    unsigned u = __float_as_uint(f);
    return (unsigned short)((u + 0x7FFFu + ((u >> 16) & 1u)) >> 16);
}
// float -> f16 bits (RNE)
__device__ __forceinline__ unsigned short f2h(float f) {
    return __half_as_ushort(__float2half(f));
}
__device__ __forceinline__ float h2f(unsigned short u) {
    return __half2float(__ushort_as_half(u));
}
// packed f16 add + per-half abs (v_pk_add_f16 + v_and_b32)
__device__ __forceinline__ unsigned pkaddabs(unsigned a, unsigned b) {
    hv2 r = __builtin_bit_cast(hv2, a) + __builtin_bit_cast(hv2, b);
    return __builtin_bit_cast(unsigned, r) & 0x7FFF7FFFu;
}
// v_dot2_f32_f16
__device__ __forceinline__ float fdot2(unsigned a, unsigned b, float c) {
    return __builtin_amdgcn_fdot2(__builtin_bit_cast(hv2, a),
                                  __builtin_bit_cast(hv2, b), c, false);
}
__device__ __forceinline__ float h2lo(unsigned a) {
    return (float)__builtin_bit_cast(hv2, a).x;
}
__device__ __forceinline__ float h2hi(unsigned a) {
    return (float)__builtin_bit_cast(hv2, a).y;
}
// butterfly add via DPP (VALU pipe, no LDS/DS traffic)
// 0xB1 quad_perm xor1 | 0x4E quad_perm xor2 | 0x141 row_half_mirror (pairs 8-grps)
// 0x140 row_mirror (pairs 16-grp halves)    | 0x128 row_ror:8 (xor8 within 16)
template <int CTRL>
__device__ __forceinline__ float dpp_add(float v) {
    int t = __builtin_amdgcn_update_dpp(0, __float_as_int(v), CTRL, 0xf, 0xf, true);
    return v + __int_as_float(t);
}

// =====================  CSR build: bucketed counting sort (R7 pipeline)  ========
// LDS-staged histograms + per-block base offsets (R8 lesson: global atomic
// cursors onto 782 targets = 2200-deep serialization + 10x write amplification).
// prepW fused into the hist launch; transform1 fused into the scatter launch
// (independent work, disjoint block ranges -> overlapped execution).

__device__ __forceinline__ void prepW_body(int pb, int t,
                                           const float* __restrict__ Wl,
                                           const float* __restrict__ Wr,
                                           const float* __restrict__ att1,
                                           const float* __restrict__ att2,
                                           uint4* __restrict__ wfrag,
                                           unsigned short* __restrict__ att1h,
                                           unsigned short* __restrict__ att2h) {
    int e = pb * 256 + t;
    if (e >= 2048) {
        int i = e - 2048;
        if (i < HID) att1h[i] = f2h(att1[i]);
        else if (i < HID + NCLS) att2h[i - HID] = f2h(att2[i - HID]);
        return;
    }
    int lane = e & 63;
    int kt = (e >> 6) & 3;
    int ct = (e >> 8) & 3;
    int mat = e >> 10;
    const float* W = mat ? Wr : Wl;
    int k0 = kt * 32 + (lane >> 4) * 8;
    int c = ct * 16 + (lane & 15);
    unsigned short h[8];
#pragma unroll
    for (int j = 0; j < 8; j++) h[j] = f2bf(W[(k0 + j) * HID + c]);
    wfrag[e] = *(uint4*)h;
}

// launch A: blocks [0,nChunks) = bucketHist; blocks [nChunks, nChunks+9) = prepW
__global__ __launch_bounds__(256) void histPrep(const int* __restrict__ ei,
                                                int Eorig, int Etot,
                                                int* __restrict__ bucketSize, int BK,
                                                int nChunks,
                                                const float* __restrict__ Wl,
                                                const float* __restrict__ Wr,
                                                const float* __restrict__ att1,
                                                const float* __restrict__ att2,
                                                uint4* __restrict__ wfrag,
                                                unsigned short* __restrict__ att1h,
                                                unsigned short* __restrict__ att2h) {
    __shared__ int h[1024];
    int t = threadIdx.x;
    if ((int)blockIdx.x >= nChunks) {
        prepW_body(blockIdx.x - nChunks, t, Wl, Wr, att1, att2, wfrag, att1h, att2h);
        return;
    }
    for (int j = t; j < BK; j += 256) h[j] = 0;
    __syncthreads();
    int base = blockIdx.x * CHUNK;
    int end = base + CHUNK < Etot ? base + CHUNK : Etot;
    for (int i = base + t; i < end; i += 256) {
        int dst = i < Eorig ? ei[Eorig + i] : i - Eorig;
        atomicAdd(&h[dst >> BSH], 1);
    }
    __syncthreads();
    for (int j = t; j < BK; j += 256)
        if (h[j]) atomicAdd(&bucketSize[j], h[j]);
}

// scan over up to 1024 buckets (4 per thread)
__global__ __launch_bounds__(256) void bucketScan(const int* __restrict__ bucketSize,
                                                  int* __restrict__ bucketStart,
                                                  int* __restrict__ bucketCursor,
                                                  int BK, int Etot) {
    __shared__ int sd[256];
    int t = threadIdx.x;
    int v[4]; int ts = 0;
#pragma unroll
    for (int k = 0; k < 4; k++) {
        v[k] = (4 * t + k < BK) ? bucketSize[4 * t + k] : 0;
        ts += v[k];
    }
    sd[t] = ts;
    __syncthreads();
    for (int off = 1; off < 256; off <<= 1) {
        int x = (t >= off) ? sd[t - off] : 0;
        __syncthreads();
        sd[t] += x;
        __syncthreads();
    }
    int excl = sd[t] - ts;
#pragma unroll
    for (int k = 0; k < 4; k++) {
        if (4 * t + k < BK) { bucketStart[4 * t + k] = excl; bucketCursor[4 * t + k] = excl; }
        excl += v[k];
    }
    if (t == 255) bucketStart[BK] = Etot;
}

// ---- transform1 body (MFMA bf16): xl/xr f16-packed, sl = 0.6*att.f16(xl) ----
__device__ __forceinline__ void transform1_body(int tb, int t, uint4* sw,
                                                const float* __restrict__ x,
                                                const uint4* __restrict__ wfrag,
                                                const float* __restrict__ bl,
                                                const float* __restrict__ br,
                                                const float* __restrict__ att,
                                                unsigned short* __restrict__ xlh,
                                                unsigned short* __restrict__ xrh,
                                                float* __restrict__ sl, int N) {
#pragma unroll
    for (int j = 0; j < 8; j++) sw[t + j * 256] = wfrag[t + j * 256];
    __syncthreads();

    int w = t >> 6, lane = t & 63;
    int nb = tb * 64 + w * 16;
    int m = lane & 15, quad = lane >> 4;

    int arow = nb + m; if (arow >= N) arow = N - 1;
    const float* xrow = x + (size_t)arow * F_IN + quad * 8;
    bf8 afr[4];
#pragma unroll
    for (int kt = 0; kt < 4; kt++) {
        float4 lo = *(const float4*)(xrow + kt * 32);
        float4 hi = *(const float4*)(xrow + kt * 32 + 4);
        unsigned short hh[8];
        hh[0] = f2bf(lo.x); hh[1] = f2bf(lo.y); hh[2] = f2bf(lo.z); hh[3] = f2bf(lo.w);
        hh[4] = f2bf(hi.x); hh[5] = f2bf(hi.y); hh[6] = f2bf(hi.z); hh[7] = f2bf(hi.w);
        afr[kt] = *(bf8*)hh;
    }

    float am[4];
#pragma unroll
    for (int ct = 0; ct < 4; ct++) am[ct] = att[ct * 16 + m];
    float slp[4] = {0.f, 0.f, 0.f, 0.f};

#pragma unroll
    for (int mat = 0; mat < 2; mat++) {
        const float* bias = mat ? br : bl;
#pragma unroll
        for (int ct = 0; ct < 4; ct++) {
            f4v acc = {0.f, 0.f, 0.f, 0.f};
#pragma unroll
            for (int kt = 0; kt < 4; kt++) {
                bf8 bfr = *(bf8*)&sw[((mat * 4 + ct) * 4 + kt) * 64 + lane];
                acc = __builtin_amdgcn_mfma_f32_16x16x32_bf16(afr[kt], bfr, acc, 0, 0, 0);
            }
            int ch = ct * 16 + m;
            float bv = bias[ch];
#pragma unroll
            for (int reg = 0; reg < 4; reg++) {
                int node = nb + quad * 4 + reg;
                float o = acc[reg] + bv;
                if (mat) {
                    if (node < N) xrh[(size_t)node * HID + ch] = f2h(o);
                } else {
                    unsigned short hb = f2h(o);
                    slp[reg] = fmaf(am[ct], h2f(hb), slp[reg]);  // att . f16(xl)
                    if (node < N) xlh[(size_t)node * HID + ch] = hb;
                }
            }
        }
    }
    // reduce slp over the 16 m-lanes — all DPP
#pragma unroll
    for (int reg = 0; reg < 4; reg++) {
        slp[reg] = dpp_add<0xB1>(slp[reg]);
        slp[reg] = dpp_add<0x4E>(slp[reg]);
        slp[reg] = dpp_add<0x141>(slp[reg]);
        slp[reg] = dpp_add<0x140>(slp[reg]);
    }
    if (m == 0) {
#pragma unroll
        for (int reg = 0; reg < 4; reg++) {
            int node = nb + quad * 4 + reg;
            if (node < N) sl[node] = 0.6f * slp[reg];
        }
    }
}

// launch B: blocks [0,nChunks) = bucketScatter; blocks [nChunks,..) = transform1.
// LDS union: transform1 uses 32KB uint4 sw; scatter carves 3x1024 ints from it.
// pairs packed: (src << 7) | (dst & 127)   — src < 2^17, fits in int
__global__ __launch_bounds__(256) void scatT1(const int* __restrict__ ei,
                                              int Eorig, int Etot,
                                              int* __restrict__ bucketCursor,
                                              int* __restrict__ pairs, int BK,
                                              int nChunks,
                                              const float* __restrict__ x,
                                              const uint4* __restrict__ wfrag,
                                              const float* __restrict__ bl,
                                              const float* __restrict__ br,
                                              const float* __restrict__ att,
                                              unsigned short* __restrict__ xlh,
                                              unsigned short* __restrict__ xrh,
                                              float* __restrict__ sl, int N) {
    __shared__ uint4 sw[2048];   // 32KB; scatter reuses as int[3][1024]
    int t = threadIdx.x;
    if ((int)blockIdx.x >= nChunks) {
        transform1_body(blockIdx.x - nChunks, t, sw, x, wfrag, bl, br, att,
                        xlh, xrh, sl, N);
        return;
    }
    int* h     = (int*)sw;
    int* lbase = h + 1024;
    int* hcur  = h + 2048;
    for (int j = t; j < BK; j += 256) { h[j] = 0; hcur[j] = 0; }
    __syncthreads();
    int base = blockIdx.x * CHUNK;
    int end = base + CHUNK < Etot ? base + CHUNK : Etot;
    for (int i = base + t; i < end; i += 256) {
        int dst = i < Eorig ? ei[Eorig + i] : i - Eorig;
        atomicAdd(&h[dst >> BSH], 1);
    }
    __syncthreads();
    for (int j = t; j < BK; j += 256)
        lbase[j] = h[j] ? atomicAdd(&bucketCursor[j], h[j]) : 0;
    __syncthreads();
    for (int i = base + t; i < end; i += 256) {
        int src, dst;
        if (i < Eorig) { src = ei[i]; dst = ei[Eorig + i]; }
        else           { src = dst = i - Eorig; }
        int b = dst >> BSH;
        int off = atomicAdd(&hcur[b], 1);
        pairs[lbase[b] + off] = (src << BSH) | (dst & BMSK);
    }
}

__global__ __launch_bounds__(256) void bucketCSR(const int* __restrict__ pairs,
                                                 const int* __restrict__ bucketStart,
                                                 int* __restrict__ rowstart,
                                                 int* __restrict__ cnt,
                                                 int* __restrict__ srclist, int N) {
    __shared__ int c[256], cur[256];
    int t = threadIdx.x;
    int b = blockIdx.x;
    int lo = b * NBKT;
    int eb = bucketStart[b], ee = bucketStart[b + 1];
    c[t] = 0;
    __syncthreads();
    for (int i = eb + t; i < ee; i += 256)
        atomicAdd(&c[pairs[i] & BMSK], 1);
    __syncthreads();
    cur[t] = c[t];
    __syncthreads();
    for (int off = 1; off < 256; off <<= 1) {
        int x = (t >= off) ? cur[t - off] : 0;
        __syncthreads();
        cur[t] += x;
        __syncthreads();
    }
    int excl = cur[t] - c[t];
    int node = lo + t;
    if (t < NBKT && node < N) { rowstart[node] = eb + excl; cnt[node] = c[t]; }
    __syncthreads();
    cur[t] = excl;
    __syncthreads();
    for (int i = eb + t; i < ee; i += 256) {
        int v = pairs[i];
        int pos = atomicAdd(&cur[v & BMSK], 1);
        srclist[eb + pos] = v >> BSH;
    }
}

// transform2: fp32 math. xl + xr emitted f16-packed. ReLU fused.
// sl[node] = 0.6 * att . f16(xl[node,:]).
__global__ __launch_bounds__(256) void transform2(const float* __restrict__ h,
                                                  const float* __restrict__ Wl,
                                                  const float* __restrict__ bl,
                                                  const float* __restrict__ Wr,
                                                  const float* __restrict__ br,
                                                  const float* __restrict__ att,
                                                  unsigned short* __restrict__ xlh,
                                                  unsigned short* __restrict__ xrh,
                                                  float* __restrict__ sl, int N) {
    __shared__ float sWl[HID * NCLS];
    __shared__ float sWr[HID * NCLS];
    __shared__ float sx[128][68];
    int t = threadIdx.x;
    int nb = blockIdx.x * 128;

#pragma unroll
    for (int j = 0; j < 2; j++) {
        int f = t + j * 256;
        ((float4*)sWl)[f] = ((const float4*)Wl)[f];
        ((float4*)sWr)[f] = ((const float4*)Wr)[f];
    }
    int maxf = (N - nb) * 16;
#pragma unroll
    for (int j = 0; j < 8; j++) {
        int f = t + j * 256;
        int node = f >> 4, kc = f & 15;
        float4 v = {0.f, 0.f, 0.f, 0.f};
        if (f < maxf) v = ((const float4*)(h + (size_t)nb * HID))[f];
        v.x = fmaxf(v.x, 0.f);
        v.y = fmaxf(v.y, 0.f);
        v.z = fmaxf(v.z, 0.f);
        v.w = fmaxf(v.w, 0.f);
        *(float4*)&sx[node][kc * 4] = v;
    }
    __syncthreads();

    int c4 = (t & 7) * 4;
    int slot = t >> 3;
    float4 bl4 = *(const float4*)(bl + c4);
    float4 br4 = *(const float4*)(br + c4);
    float4 at4 = *(const float4*)(att + c4);
    float4 accl[4] = {bl4, bl4, bl4, bl4};
    float4 accr[4] = {br4, br4, br4, br4};

#pragma unroll 4
    for (int k4 = 0; k4 < HID / 4; k4++) {
        int k = k4 * 4;
        float4 wl0 = *(const float4*)&sWl[(k + 0) * NCLS + c4];
        float4 wl1 = *(const float4*)&sWl[(k + 1) * NCLS + c4];
        float4 wl2 = *(const float4*)&sWl[(k + 2) * NCLS + c4];
        float4 wl3 = *(const float4*)&sWl[(k + 3) * NCLS + c4];
        float4 wr0 = *(const float4*)&sWr[(k + 0) * NCLS + c4];
        float4 wr1 = *(const float4*)&sWr[(k + 1) * NCLS + c4];
        float4 wr2 = *(const float4*)&sWr[(k + 2) * NCLS + c4];
        float4 wr3 = *(const float4*)&sWr[(k + 3) * NCLS + c4];
#pragma unroll
        for (int j = 0; j < 4; j++) {
            float4 xv = *(const float4*)&sx[slot + j * 32][k];
            f4fma(accl[j], xv.x, wl0); f4fma(accr[j], xv.x, wr0);
            f4fma(accl[j], xv.y, wl1); f4fma(accr[j], xv.y, wr1);
            f4fma(accl[j], xv.z, wl2); f4fma(accr[j], xv.z, wr2);
            f4fma(accl[j], xv.w, wl3); f4fma(accr[j], xv.w, wr3);
        }
    }
#pragma unroll
    for (int j = 0; j < 4; j++) {
        ushort4 o;
        o.x = f2h(accl[j].x); o.y = f2h(accl[j].y);
        o.z = f2h(accl[j].z); o.w = f2h(accl[j].w);
        ushort4 orr;
        orr.x = f2h(accr[j].x); orr.y = f2h(accr[j].y);
        orr.z = f2h(accr[j].z); orr.w = f2h(accr[j].w);
        float slpj = fmaf(at4.x, h2f(o.x),
                     fmaf(at4.y, h2f(o.y),
                     fmaf(at4.z, h2f(o.z), at4.w * h2f(o.w))));
        slpj = dpp_add<0xB1>(slpj);
        slpj = dpp_add<0x4E>(slpj);
        slpj = dpp_add<0x141>(slpj);
        int g = nb + slot + j * 32;
        if (g < N) {
            *(ushort4*)(xlh + (size_t)g * NCLS + c4) = o;
            *(ushort4*)(xrh + (size_t)g * NCLS + c4) = orr;
            if ((t & 7) == 0) sl[g] = 0.6f * slpj;
        }
    }
}

// =====================  fused softmax aggregation v13 (R7 ping-pong)  ===========
// 2-deep ping-pong is the empirical optimum (R9: 4-deep cost occupancy, -33%).
// logit (shifted): p = 0.4*sum_c att_c|u_c| + sl_src  (per-dst terms cancel).
#define LOADROW(VP, SRC)                                                  \
    {                                                                     \
        const unsigned short* rp = xlh + (unsigned)(SRC) * C + cb0;       \
        if (NH == 4) *(uint4*)(VP) = *(const uint4*)rp;                   \
        else         *(uint2*)(VP) = *(const uint2*)rp;                   \
    }

#define COMPUTE(VP, T, B)                                                 \
    {                                                                     \
        float pa = 0.f;                                                   \
        _Pragma("unroll")                                                 \
        for (int j = 0; j < NH; j++)                                      \
            pa = fdot2(pkaddabs((VP)[j], xrp[j]), atp[j], pa);            \
        pa = dpp_add<0x128>(pa);                                          \
        pa += __shfl_xor(pa, 16, 64);                                     \
        pa += __shfl_xor(pa, 32, 64);                                     \
        float wgt = ((B) * 8 + slot < len) ? __expf(fmaf(0.4f, pa, (T)))  \
                                           : 0.f;                         \
        s += wgt;                                                         \
        _Pragma("unroll")                                                 \
        for (int j = 0; j < NH; j++) {                                    \
            acc[2 * j]     = fmaf(wgt, h2lo((VP)[j]), acc[2 * j]);        \
            acc[2 * j + 1] = fmaf(wgt, h2hi((VP)[j]), acc[2 * j + 1]);    \
        }                                                                 \
    }

template <int C>
__global__ __launch_bounds__(256) void fusedAggG(const unsigned short* __restrict__ xlh,
                                                 const unsigned short* __restrict__ xrh,
                                                 const unsigned short* __restrict__ atth,
                                                 const float* __restrict__ sl,
                                                 const int* __restrict__ rowstart,
                                                 const int* __restrict__ cnt,
                                                 const int* __restrict__ srclist,
                                                 const float* __restrict__ bias,
                                                 float* __restrict__ out, int N) {
    constexpr int CH = C / 8;      // channels per lane: 8 (C=64) / 4 (C=32)
    constexpr int NH = CH / 2;     // packed-pair regs
    int wid = threadIdx.x >> 6;
    int lane = threadIdx.x & 63;
    int n = blockIdx.x * 4 + wid;
    if (n >= N) return;

    int slot = lane & 7;           // edge within batch  (bits 0-2)
    int pos  = lane >> 3;          // channel group      (bits 3-5)
    int cb0  = pos * CH;

    unsigned xrp[NH], atp[NH];
    if (NH == 4) {
        *(uint4*)xrp = *(const uint4*)(xrh + (size_t)n * C + cb0);
        *(uint4*)atp = *(const uint4*)(atth + cb0);
    } else {
        *(uint2*)xrp = *(const uint2*)(xrh + (size_t)n * C + cb0);
        *(uint2*)atp = *(const uint2*)(atth + cb0);
    }

    int row = rowstart[n];
    int deg = cnt[n];

    float s = 0.f;
    float acc[CH];
#pragma unroll
    for (int c = 0; c < CH; c++) acc[c] = 0.f;

    for (int cb = 0; cb < deg; cb += 64) {
        int len = deg - cb; if (len > 64) len = 64;
        int len1 = len - 1;
        int li = lane < len ? lane : len1;
        int srcv = srclist[row + cb + li];
        float slv = sl[srcv];                 // per-chunk gather; shuffled per batch
        int nbatch = (len + 7) >> 3;

        // prefetch batch 0 -> A
        float tA = __shfl(slv, slot, 64);
        int srcA = __shfl(srcv, slot, 64);
        unsigned vpA[NH], vpB[NH];
        float tB;
        LOADROW(vpA, srcA)

        int b = 0;
        while (true) {
            bool moreB = (b + 1 < nbatch);
            if (moreB) {
                int e = (b + 1) * 8 + slot;
                tB = __shfl(slv, e, 64);
                int srcB = __shfl(srcv, e, 64);
                LOADROW(vpB, srcB)
            }
            COMPUTE(vpA, tA, b)
            if (!moreB) break;
            bool moreA = (b + 2 < nbatch);
            if (moreA) {
                int e = (b + 2) * 8 + slot;
                tA = __shfl(slv, e, 64);
                int srcA2 = __shfl(srcv, e, 64);
                LOADROW(vpA, srcA2)
            }
            COMPUTE(vpB, tB, b + 1)
            if (!moreA) break;
            b += 2;
        }
    }
    // cross-slot reduce over lane bits 0,1,2 — all DPP (VALU), zero DS ops
#pragma unroll
    for (int c = 0; c < CH; c++) {
        acc[c] = dpp_add<0xB1>(acc[c]);    // xor1
        acc[c] = dpp_add<0x4E>(acc[c]);    // xor2
        acc[c] = dpp_add<0x141>(acc[c]);   // half_mirror (completes 8-lane sum)
    }
    s = dpp_add<0xB1>(s);
    s = dpp_add<0x4E>(s);
    s = dpp_add<0x141>(s);

    if (slot == 0) {
        float inv = 1.f / (s + 1e-16f);
        float o8[CH];
        float bi[CH];
        if (NH == 4) {
            *(float4*)&bi[0] = *(const float4*)(bias + cb0);
            *(float4*)&bi[4] = *(const float4*)(bias + cb0 + 4);
        } else {
            *(float4*)&bi[0] = *(const float4*)(bias + cb0);
        }
#pragma unroll
        for (int c = 0; c < CH; c++) o8[c] = fmaf(acc[c], inv, bi[c]);
        if (NH == 4) {
            *(float4*)(out + (size_t)n * C + cb0)     = *(float4*)&o8[0];
            *(float4*)(out + (size_t)n * C + cb0 + 4) = *(float4*)&o8[4];
        } else {
            *(float4*)(out + (size_t)n * C + cb0) = *(float4*)&o8[0];
        }
    }
}

extern "C" void kernel_launch(void* const* d_in, const int* in_sizes, int n_in,
                              void* d_out, int out_size, void* d_ws, size_t ws_size,
                              hipStream_t stream) {
    const float* x     = (const float*)d_in[0];
    const int*   ei    = (const int*)d_in[1];
    const float* W1l   = (const float*)d_in[2];
    const float* b1l   = (const float*)d_in[3];
    const float* W1r   = (const float*)d_in[4];
    const float* b1r   = (const float*)d_in[5];
    const float* att1  = (const float*)d_in[6];
    const float* bias1 = (const float*)d_in[7];
    const float* W2l   = (const float*)d_in[8];
    const float* b2l   = (const float*)d_in[9];
    const float* W2r   = (const float*)d_in[10];
    const float* b2r   = (const float*)d_in[11];
    const float* att2  = (const float*)d_in[12];
    const float* bias2 = (const float*)d_in[13];
    float* out = (float*)d_out;

    int N     = in_sizes[0] / F_IN;   // 100000
    int Eorig = in_sizes[1] / 2;      // 1600000
    int Etot  = Eorig + N;
    int BK    = (N + NBKT - 1) / NBKT;   // 782 buckets (<=1024)

    char* p = (char*)d_ws;
    auto alloc = [&](size_t bytes) { void* r = (void*)p; p += (bytes + 255) & ~(size_t)255; return r; };
    unsigned short* xl1h = (unsigned short*)alloc((size_t)N * HID * 2);   // f16 table L1
    unsigned short* xr1h = (unsigned short*)alloc((size_t)N * HID * 2);   // f16 xr L1
    float* h       = (float*)alloc((size_t)N * HID * 4);
    unsigned short* xl2h = (unsigned short*)alloc((size_t)N * NCLS * 2);  // f16 table L2
    unsigned short* xr2h = (unsigned short*)alloc((size_t)N * NCLS * 2);  // f16 xr L2
    int*   cnt     = (int*)alloc((size_t)N * 4);
    int*   rowstart= (int*)alloc((size_t)N * 4);
    int*   srclist = (int*)alloc((size_t)Etot * 4);
    uint4* wfrag   = (uint4*)alloc(2048 * 16);   // frag-ordered bf16 W1
    float* sl1     = (float*)alloc((size_t)N * 4);   // 0.6*att1.xl1 per node
    float* sl2     = (float*)alloc((size_t)N * 4);   // 0.6*att2.xl2 per node
    unsigned short* att1h = (unsigned short*)alloc(HID * 2);
    unsigned short* att2h = (unsigned short*)alloc(NCLS * 2);
    int*   bucketSize   = (int*)alloc(1040 * 4);
    int*   bucketStart  = (int*)alloc(1040 * 4);
    int*   bucketCursor = (int*)alloc(1040 * 4);
    // packed pairs (6.8MB) aliased over h (25.6MB, dead during CSR build)
    int*   pairs   = (int*)h;

    int nChunks = (Etot + CHUNK - 1) / CHUNK;      // 416
    int nT1     = (N + 63) / 64;                   // 1563

    // ---- CSR build + layer-1 prep, with independent work overlapped ----
    hipMemsetAsync(bucketSize, 0, 1040 * 4, stream);
    histPrep<<<nChunks + 9, 256, 0, stream>>>(ei, Eorig, Etot, bucketSize, BK, nChunks,
                                              W1l, W1r, att1, att2, wfrag, att1h, att2h);
    bucketScan<<<1, 256, 0, stream>>>(bucketSize, bucketStart, bucketCursor, BK, Etot);
    scatT1<<<nChunks + nT1, 256, 0, stream>>>(ei, Eorig, Etot, bucketCursor, pairs, BK,
                                              nChunks, x, wfrag, b1l, b1r, att1,
                                              xl1h, xr1h, sl1, N);
    bucketCSR<<<BK, 256, 0, stream>>>(pairs, bucketStart, rowstart, cnt, srclist, N);

    // ---- layer 1 aggregation ----
    fusedAggG<HID><<<(N + 3) / 4, 256, 0, stream>>>(xl1h, xr1h, att1h, sl1, rowstart, cnt,
                                                    srclist, bias1, h, N);

    // ---- layer 2 ----
    transform2<<<(N + 127) / 128, 256, 0, stream>>>(h, W2l, b2l, W2r, b2r, att2, xl2h, xr2h, sl2, N);
    fusedAggG<NCLS><<<(N + 3) / 4, 256, 0, stream>>>(xl2h, xr2h, att2h, sl2, rowstart, cnt,
                                                     srclist, bias2, out, N);
}

// Round 11
// 291.953 us; speedup vs baseline: 2.4478x; 1.0344x over previous
//
#include <hip/hip_runtime.h>
#include <hip/hip_fp16.h>
#include <math.h>

#define F_IN 128
#define HID 64
#define NCLS 32
#define NEG 0.2f
#define NBKT 128          // nodes per bucket (dst >> 7)
#define BSH 7
#define BMSK 127
#define CHUNK 4096        // edges per block in bucket passes

using bf8 = __attribute__((ext_vector_type(8))) short;   // 8 bf16 (4 VGPRs)
using f4v = __attribute__((ext_vector_type(4))) float;   // MFMA acc
typedef _Float16 hv2 __attribute__((ext_vector_type(2)));

__device__ __forceinline__ void f4fma(float4& a, float s, const float4& w) {
    a.x = fmaf(s, w.x, a.x);
    a.y = fmaf(s, w.y, a.y);
    a.z = fmaf(s, w.z, a.z);
    a.w = fmaf(s, w.w, a.w);
}
// float -> bf16 (round to nearest even)
__device__ __forceinline__ unsigned short f2bf(float f) {
    unsigned u = __float_as_uint(f);
    return (unsigned short)((u + 0x7FFFu + ((u >> 16) & 1u)) >> 16);
}
// float -> f16 bits (RNE)
__device__ __forceinline__ unsigned short f2h(float f) {
    return __half_as_ushort(__float2half(f));
}
__device__ __forceinline__ float h2f(unsigned short u) {
    return __half2float(__ushort_as_half(u));
}
// packed f16 add + per-half abs (v_pk_add_f16 + v_and_b32)
__device__ __forceinline__ unsigned pkaddabs(unsigned a, unsigned b) {
    hv2 r = __builtin_bit_cast(hv2, a) + __builtin_bit_cast(hv2, b);
    return __builtin_bit_cast(unsigned, r) & 0x7FFF7FFFu;
}
// v_dot2_f32_f16
__device__ __forceinline__ float fdot2(unsigned a, unsigned b, float c) {
    return __builtin_amdgcn_fdot2(__builtin_bit_cast(hv2, a),
                                  __builtin_bit_cast(hv2, b), c, false);
}
__device__ __forceinline__ float h2lo(unsigned a) {
    return (float)__builtin_bit_cast(hv2, a).x;
}
__device__ __forceinline__ float h2hi(unsigned a) {
    return (float)__builtin_bit_cast(hv2, a).y;
}
// butterfly add via DPP (VALU pipe, no LDS/DS traffic)
// 0xB1 quad_perm xor1 | 0x4E quad_perm xor2 | 0x141 row_half_mirror (pairs 8-grps)
// 0x140 row_mirror (pairs 16-grp halves)    | 0x128 row_ror:8 (xor8 within 16)
template <int CTRL>
__device__ __forceinline__ float dpp_add(float v) {
    int t = __builtin_amdgcn_update_dpp(0, __float_as_int(v), CTRL, 0xf, 0xf, true);
    return v + __int_as_float(t);
}

// =====================  CSR build: bucketed counting sort  =====================
// LDS-staged histograms + per-block base offsets (R8 lesson: global atomic
// cursors onto 782 targets = 2200-deep serialization + 10x write amplification).
// prepW fused into hist launch (harmless, R10); scatter/transform1 kept SEPARATE
// (R10 lesson: fusing them cost occupancy + bank conflicts, +3us).

__device__ __forceinline__ void prepW_body(int pb, int t,
                                           const float* __restrict__ Wl,
                                           const float* __restrict__ Wr,
                                           const float* __restrict__ att1,
                                           const float* __restrict__ att2,
                                           uint4* __restrict__ wfrag,
                                           unsigned short* __restrict__ att1h,
                                           unsigned short* __restrict__ att2h) {
    int e = pb * 256 + t;
    if (e >= 2048) {
        int i = e - 2048;
        if (i < HID) att1h[i] = f2h(att1[i]);
        else if (i < HID + NCLS) att2h[i - HID] = f2h(att2[i - HID]);
        return;
    }
    int lane = e & 63;
    int kt = (e >> 6) & 3;
    int ct = (e >> 8) & 3;
    int mat = e >> 10;
    const float* W = mat ? Wr : Wl;
    int k0 = kt * 32 + (lane >> 4) * 8;
    int c = ct * 16 + (lane & 15);
    unsigned short h[8];
#pragma unroll
    for (int j = 0; j < 8; j++) h[j] = f2bf(W[(k0 + j) * HID + c]);
    wfrag[e] = *(uint4*)h;
}

// launch A: blocks [0,nChunks) = bucketHist; blocks [nChunks, nChunks+9) = prepW
__global__ __launch_bounds__(256) void histPrep(const int* __restrict__ ei,
                                                int Eorig, int Etot,
                                                int* __restrict__ bucketSize, int BK,
                                                int nChunks,
                                                const float* __restrict__ Wl,
                                                const float* __restrict__ Wr,
                                                const float* __restrict__ att1,
                                                const float* __restrict__ att2,
                                                uint4* __restrict__ wfrag,
                                                unsigned short* __restrict__ att1h,
                                                unsigned short* __restrict__ att2h) {
    __shared__ int h[1024];
    int t = threadIdx.x;
    if ((int)blockIdx.x >= nChunks) {
        prepW_body(blockIdx.x - nChunks, t, Wl, Wr, att1, att2, wfrag, att1h, att2h);
        return;
    }
    for (int j = t; j < BK; j += 256) h[j] = 0;
    __syncthreads();
    int base = blockIdx.x * CHUNK;
    int end = base + CHUNK < Etot ? base + CHUNK : Etot;
    for (int i = base + t; i < end; i += 256) {
        int dst = i < Eorig ? ei[Eorig + i] : i - Eorig;
        atomicAdd(&h[dst >> BSH], 1);
    }
    __syncthreads();
    for (int j = t; j < BK; j += 256)
        if (h[j]) atomicAdd(&bucketSize[j], h[j]);
}

// scan over up to 1024 buckets (4 per thread)
__global__ __launch_bounds__(256) void bucketScan(const int* __restrict__ bucketSize,
                                                  int* __restrict__ bucketStart,
                                                  int* __restrict__ bucketCursor,
                                                  int BK, int Etot) {
    __shared__ int sd[256];
    int t = threadIdx.x;
    int v[4]; int ts = 0;
#pragma unroll
    for (int k = 0; k < 4; k++) {
        v[k] = (4 * t + k < BK) ? bucketSize[4 * t + k] : 0;
        ts += v[k];
    }
    sd[t] = ts;
    __syncthreads();
    for (int off = 1; off < 256; off <<= 1) {
        int x = (t >= off) ? sd[t - off] : 0;
        __syncthreads();
        sd[t] += x;
        __syncthreads();
    }
    int excl = sd[t] - ts;
#pragma unroll
    for (int k = 0; k < 4; k++) {
        if (4 * t + k < BK) { bucketStart[4 * t + k] = excl; bucketCursor[4 * t + k] = excl; }
        excl += v[k];
    }
    if (t == 255) bucketStart[BK] = Etot;
}

// pairs packed: (src << 7) | (dst & 127)   — src < 2^17, fits in int
__global__ __launch_bounds__(256) void bucketScatter(const int* __restrict__ ei,
                                                     int Eorig, int Etot,
                                                     int* __restrict__ bucketCursor,
                                                     int* __restrict__ pairs, int BK) {
    __shared__ int h[1024], lbase[1024], hcur[1024];
    int t = threadIdx.x;
    for (int j = t; j < BK; j += 256) { h[j] = 0; hcur[j] = 0; }
    __syncthreads();
    int base = blockIdx.x * CHUNK;
    int end = base + CHUNK < Etot ? base + CHUNK : Etot;
    for (int i = base + t; i < end; i += 256) {
        int dst = i < Eorig ? ei[Eorig + i] : i - Eorig;
        atomicAdd(&h[dst >> BSH], 1);
    }
    __syncthreads();
    for (int j = t; j < BK; j += 256)
        lbase[j] = h[j] ? atomicAdd(&bucketCursor[j], h[j]) : 0;
    __syncthreads();
    for (int i = base + t; i < end; i += 256) {
        int src, dst;
        if (i < Eorig) { src = ei[i]; dst = ei[Eorig + i]; }
        else           { src = dst = i - Eorig; }
        int b = dst >> BSH;
        int off = atomicAdd(&hcur[b], 1);
        pairs[lbase[b] + off] = (src << BSH) | (dst & BMSK);
    }
}

__global__ __launch_bounds__(256) void bucketCSR(const int* __restrict__ pairs,
                                                 const int* __restrict__ bucketStart,
                                                 int* __restrict__ rowstart,
                                                 int* __restrict__ cnt,
                                                 int* __restrict__ srclist, int N) {
    __shared__ int c[256], cur[256];
    int t = threadIdx.x;
    int b = blockIdx.x;
    int lo = b * NBKT;
    int eb = bucketStart[b], ee = bucketStart[b + 1];
    c[t] = 0;
    __syncthreads();
    for (int i = eb + t; i < ee; i += 256)
        atomicAdd(&c[pairs[i] & BMSK], 1);
    __syncthreads();
    cur[t] = c[t];
    __syncthreads();
    for (int off = 1; off < 256; off <<= 1) {
        int x = (t >= off) ? cur[t - off] : 0;
        __syncthreads();
        cur[t] += x;
        __syncthreads();
    }
    int excl = cur[t] - c[t];
    int node = lo + t;
    if (t < NBKT && node < N) { rowstart[node] = eb + excl; cnt[node] = c[t]; }
    __syncthreads();
    cur[t] = excl;
    __syncthreads();
    for (int i = eb + t; i < ee; i += 256) {
        int v = pairs[i];
        int pos = atomicAdd(&cur[v & BMSK], 1);
        srclist[eb + pos] = v >> BSH;
    }
}

// =====================  transform1: MFMA bf16 (standalone)  =====================
// xl and xr both emitted f16-packed. sl[node] = 0.6 * att . f16(xl[node,:]).
__global__ __launch_bounds__(256) void transform1(const float* __restrict__ x,
                                                  const uint4* __restrict__ wfrag,
                                                  const float* __restrict__ bl,
                                                  const float* __restrict__ br,
                                                  const float* __restrict__ att,
                                                  unsigned short* __restrict__ xlh,
                                                  unsigned short* __restrict__ xrh,
                                                  float* __restrict__ sl, int N) {
    __shared__ uint4 sw[2048];   // 32KB frag-ordered W (both matrices)
    int t = threadIdx.x;
#pragma unroll
    for (int j = 0; j < 8; j++) sw[t + j * 256] = wfrag[t + j * 256];
    __syncthreads();

    int w = t >> 6, lane = t & 63;
    int nb = blockIdx.x * 64 + w * 16;
    int m = lane & 15, quad = lane >> 4;

    int arow = nb + m; if (arow >= N) arow = N - 1;
    const float* xrow = x + (size_t)arow * F_IN + quad * 8;
    bf8 afr[4];
#pragma unroll
    for (int kt = 0; kt < 4; kt++) {
        float4 lo = *(const float4*)(xrow + kt * 32);
        float4 hi = *(const float4*)(xrow + kt * 32 + 4);
        unsigned short hh[8];
        hh[0] = f2bf(lo.x); hh[1] = f2bf(lo.y); hh[2] = f2bf(lo.z); hh[3] = f2bf(lo.w);
        hh[4] = f2bf(hi.x); hh[5] = f2bf(hi.y); hh[6] = f2bf(hi.z); hh[7] = f2bf(hi.w);
        afr[kt] = *(bf8*)hh;
    }

    float am[4];
#pragma unroll
    for (int ct = 0; ct < 4; ct++) am[ct] = att[ct * 16 + m];
    float slp[4] = {0.f, 0.f, 0.f, 0.f};

#pragma unroll
    for (int mat = 0; mat < 2; mat++) {
        const float* bias = mat ? br : bl;
#pragma unroll
        for (int ct = 0; ct < 4; ct++) {
            f4v acc = {0.f, 0.f, 0.f, 0.f};
#pragma unroll
            for (int kt = 0; kt < 4; kt++) {
                bf8 bfr = *(bf8*)&sw[((mat * 4 + ct) * 4 + kt) * 64 + lane];
                acc = __builtin_amdgcn_mfma_f32_16x16x32_bf16(afr[kt], bfr, acc, 0, 0, 0);
            }
            int ch = ct * 16 + m;
            float bv = bias[ch];
#pragma unroll
            for (int reg = 0; reg < 4; reg++) {
                int node = nb + quad * 4 + reg;
                float o = acc[reg] + bv;
                if (mat) {
                    if (node < N) xrh[(size_t)node * HID + ch] = f2h(o);
                } else {
                    unsigned short hb = f2h(o);
                    slp[reg] = fmaf(am[ct], h2f(hb), slp[reg]);  // att . f16(xl)
                    if (node < N) xlh[(size_t)node * HID + ch] = hb;
                }
            }
        }
    }
    // reduce slp over the 16 m-lanes — all DPP
#pragma unroll
    for (int reg = 0; reg < 4; reg++) {
        slp[reg] = dpp_add<0xB1>(slp[reg]);
        slp[reg] = dpp_add<0x4E>(slp[reg]);
        slp[reg] = dpp_add<0x141>(slp[reg]);
        slp[reg] = dpp_add<0x140>(slp[reg]);
    }
    if (m == 0) {
#pragma unroll
        for (int reg = 0; reg < 4; reg++) {
            int node = nb + quad * 4 + reg;
            if (node < N) sl[node] = 0.6f * slp[reg];
        }
    }
}

// transform2: fp32 math, reads f16 h (relu fused on unpack). xl + xr f16 out.
// sl[node] = 0.6 * att . f16(xl[node,:]).
__global__ __launch_bounds__(256) void transform2(const unsigned short* __restrict__ hh,
                                                  const float* __restrict__ Wl,
                                                  const float* __restrict__ bl,
                                                  const float* __restrict__ Wr,
                                                  const float* __restrict__ br,
                                                  const float* __restrict__ att,
                                                  unsigned short* __restrict__ xlh,
                                                  unsigned short* __restrict__ xrh,
                                                  float* __restrict__ sl, int N) {
    __shared__ float sWl[HID * NCLS];
    __shared__ float sWr[HID * NCLS];
    __shared__ float sx[128][68];
    int t = threadIdx.x;
    int nb = blockIdx.x * 128;

#pragma unroll
    for (int j = 0; j < 2; j++) {
        int f = t + j * 256;
        ((float4*)sWl)[f] = ((const float4*)Wl)[f];
        ((float4*)sWr)[f] = ((const float4*)Wr)[f];
    }
    int maxf = (N - nb) * 8;     // uint4 (8 f16) units in this block
#pragma unroll
    for (int j = 0; j < 4; j++) {
        int f = t + j * 256;     // 0..1023 = 128 nodes x 8 uint4
        int node = f >> 3, kc = f & 7;
        uint4 q = {0u, 0u, 0u, 0u};
        if (f < maxf) q = ((const uint4*)(hh + (size_t)nb * HID))[f];
        float4 a, b4;
        a.x = fmaxf(h2lo(q.x), 0.f); a.y = fmaxf(h2hi(q.x), 0.f);
        a.z = fmaxf(h2lo(q.y), 0.f); a.w = fmaxf(h2hi(q.y), 0.f);
        b4.x = fmaxf(h2lo(q.z), 0.f); b4.y = fmaxf(h2hi(q.z), 0.f);
        b4.z = fmaxf(h2lo(q.w), 0.f); b4.w = fmaxf(h2hi(q.w), 0.f);
        *(float4*)&sx[node][kc * 8]     = a;
        *(float4*)&sx[node][kc * 8 + 4] = b4;
    }
    __syncthreads();

    int c4 = (t & 7) * 4;
    int slot = t >> 3;
    float4 bl4 = *(const float4*)(bl + c4);
    float4 br4 = *(const float4*)(br + c4);
    float4 at4 = *(const float4*)(att + c4);
    float4 accl[4] = {bl4, bl4, bl4, bl4};
    float4 accr[4] = {br4, br4, br4, br4};

#pragma unroll 4
    for (int k4 = 0; k4 < HID / 4; k4++) {
        int k = k4 * 4;
        float4 wl0 = *(const float4*)&sWl[(k + 0) * NCLS + c4];
        float4 wl1 = *(const float4*)&sWl[(k + 1) * NCLS + c4];
        float4 wl2 = *(const float4*)&sWl[(k + 2) * NCLS + c4];
        float4 wl3 = *(const float4*)&sWl[(k + 3) * NCLS + c4];
        float4 wr0 = *(const float4*)&sWr[(k + 0) * NCLS + c4];
        float4 wr1 = *(const float4*)&sWr[(k + 1) * NCLS + c4];
        float4 wr2 = *(const float4*)&sWr[(k + 2) * NCLS + c4];
        float4 wr3 = *(const float4*)&sWr[(k + 3) * NCLS + c4];
#pragma unroll
        for (int j = 0; j < 4; j++) {
            float4 xv = *(const float4*)&sx[slot + j * 32][k];
            f4fma(accl[j], xv.x, wl0); f4fma(accr[j], xv.x, wr0);
            f4fma(accl[j], xv.y, wl1); f4fma(accr[j], xv.y, wr1);
            f4fma(accl[j], xv.z, wl2); f4fma(accr[j], xv.z, wr2);
            f4fma(accl[j], xv.w, wl3); f4fma(accr[j], xv.w, wr3);
        }
    }
#pragma unroll
    for (int j = 0; j < 4; j++) {
        ushort4 o;
        o.x = f2h(accl[j].x); o.y = f2h(accl[j].y);
        o.z = f2h(accl[j].z); o.w = f2h(accl[j].w);
        ushort4 orr;
        orr.x = f2h(accr[j].x); orr.y = f2h(accr[j].y);
        orr.z = f2h(accr[j].z); orr.w = f2h(accr[j].w);
        float slpj = fmaf(at4.x, h2f(o.x),
                     fmaf(at4.y, h2f(o.y),
                     fmaf(at4.z, h2f(o.z), at4.w * h2f(o.w))));
        slpj = dpp_add<0xB1>(slpj);
        slpj = dpp_add<0x4E>(slpj);
        slpj = dpp_add<0x141>(slpj);
        int g = nb + slot + j * 32;
        if (g < N) {
            *(ushort4*)(xlh + (size_t)g * NCLS + c4) = o;
            *(ushort4*)(xrh + (size_t)g * NCLS + c4) = orr;
            if ((t & 7) == 0) sl[g] = 0.6f * slpj;
        }
    }
}

// =====================  fused softmax aggregation v15  =====================
// R7 2-deep ping-pong core (empirical optimum: 4-deep cost occupancy -33%, R9).
// NEW: 8 nodes/block (2 per wave, sequential) to amortize block churn;
//      HOUT templates the output as f16 (layer 1: halves agg WRITE_SIZE).
// logit (shifted): p = 0.4*sum_c att_c|u_c| + sl_src  (per-dst terms cancel).
#define LOADROW(VP, SRC)                                                  \
    {                                                                     \
        const unsigned short* rp = xlh + (unsigned)(SRC) * C + cb0;       \
        if (NH == 4) *(uint4*)(VP) = *(const uint4*)rp;                   \
        else         *(uint2*)(VP) = *(const uint2*)rp;                   \
    }

#define COMPUTE(VP, T, B)                                                 \
    {                                                                     \
        float pa = 0.f;                                                   \
        _Pragma("unroll")                                                 \
        for (int j = 0; j < NH; j++)                                      \
            pa = fdot2(pkaddabs((VP)[j], xrp[j]), atp[j], pa);            \
        pa = dpp_add<0x128>(pa);                                          \
        pa += __shfl_xor(pa, 16, 64);                                     \
        pa += __shfl_xor(pa, 32, 64);                                     \
        float wgt = ((B) * 8 + slot < len) ? __expf(fmaf(0.4f, pa, (T)))  \
                                           : 0.f;                         \
        s += wgt;                                                         \
        _Pragma("unroll")                                                 \
        for (int j = 0; j < NH; j++) {                                    \
            acc[2 * j]     = fmaf(wgt, h2lo((VP)[j]), acc[2 * j]);        \
            acc[2 * j + 1] = fmaf(wgt, h2hi((VP)[j]), acc[2 * j + 1]);    \
        }                                                                 \
    }

template <int C, bool HOUT>
__global__ __launch_bounds__(256) void fusedAggG(const unsigned short* __restrict__ xlh,
                                                 const unsigned short* __restrict__ xrh,
                                                 const unsigned short* __restrict__ atth,
                                                 const float* __restrict__ sl,
                                                 const int* __restrict__ rowstart,
                                                 const int* __restrict__ cnt,
                                                 const int* __restrict__ srclist,
                                                 const float* __restrict__ bias,
                                                 void* __restrict__ outp, int N) {
    constexpr int CH = C / 8;      // channels per lane: 8 (C=64) / 4 (C=32)
    constexpr int NH = CH / 2;     // packed-pair regs
    int wid = threadIdx.x >> 6;
    int lane = threadIdx.x & 63;

    int slot = lane & 7;           // edge within batch  (bits 0-2)
    int pos  = lane >> 3;          // channel group      (bits 3-5)
    int cb0  = pos * CH;

    for (int rep = 0; rep < 2; rep++) {
        int n = blockIdx.x * 8 + rep * 4 + wid;
        if (n >= N) break;

        unsigned xrp[NH], atp[NH];
        if (NH == 4) {
            *(uint4*)xrp = *(const uint4*)(xrh + (size_t)n * C + cb0);
            *(uint4*)atp = *(const uint4*)(atth + cb0);
        } else {
            *(uint2*)xrp = *(const uint2*)(xrh + (size_t)n * C + cb0);
            *(uint2*)atp = *(const uint2*)(atth + cb0);
        }

        int row = rowstart[n];
        int deg = cnt[n];

        float s = 0.f;
        float acc[CH];
#pragma unroll
        for (int c = 0; c < CH; c++) acc[c] = 0.f;

        for (int cb = 0; cb < deg; cb += 64) {
            int len = deg - cb; if (len > 64) len = 64;
            int len1 = len - 1;
            int li = lane < len ? lane : len1;
            int srcv = srclist[row + cb + li];
            float slv = sl[srcv];             // per-chunk gather; shuffled per batch
            int nbatch = (len + 7) >> 3;

            // prefetch batch 0 -> A
            float tA = __shfl(slv, slot, 64);
            int srcA = __shfl(srcv, slot, 64);
            unsigned vpA[NH], vpB[NH];
            float tB;
            LOADROW(vpA, srcA)

            int b = 0;
            while (true) {
                bool moreB = (b + 1 < nbatch);
                if (moreB) {
                    int e = (b + 1) * 8 + slot;
                    tB = __shfl(slv, e, 64);
                    int srcB = __shfl(srcv, e, 64);
                    LOADROW(vpB, srcB)
                }
                COMPUTE(vpA, tA, b)
                if (!moreB) break;
                bool moreA = (b + 2 < nbatch);
                if (moreA) {
                    int e = (b + 2) * 8 + slot;
                    tA = __shfl(slv, e, 64);
                    int srcA2 = __shfl(srcv, e, 64);
                    LOADROW(vpA, srcA2)
                }
                COMPUTE(vpB, tB, b + 1)
                if (!moreA) break;
                b += 2;
            }
        }
        // cross-slot reduce over lane bits 0,1,2 — all DPP (VALU), zero DS ops
#pragma unroll
        for (int c = 0; c < CH; c++) {
            acc[c] = dpp_add<0xB1>(acc[c]);    // xor1
            acc[c] = dpp_add<0x4E>(acc[c]);    // xor2
            acc[c] = dpp_add<0x141>(acc[c]);   // half_mirror (completes 8-lane sum)
        }
        s = dpp_add<0xB1>(s);
        s = dpp_add<0x4E>(s);
        s = dpp_add<0x141>(s);

        if (slot == 0) {
            float inv = 1.f / (s + 1e-16f);
            float o8[CH];
            float bi[CH];
            if (NH == 4) {
                *(float4*)&bi[0] = *(const float4*)(bias + cb0);
                *(float4*)&bi[4] = *(const float4*)(bias + cb0 + 4);
            } else {
                *(float4*)&bi[0] = *(const float4*)(bias + cb0);
            }
#pragma unroll
            for (int c = 0; c < CH; c++) o8[c] = fmaf(acc[c], inv, bi[c]);
            if (HOUT) {
                unsigned short oh[CH];
#pragma unroll
                for (int c = 0; c < CH; c++) oh[c] = f2h(o8[c]);
                unsigned short* op = (unsigned short*)outp + (size_t)n * C + cb0;
                if (NH == 4) *(uint4*)op = *(uint4*)oh;
                else         *(uint2*)op = *(uint2*)oh;
            } else {
                float* op = (float*)outp + (size_t)n * C + cb0;
                if (NH == 4) {
                    *(float4*)op       = *(float4*)&o8[0];
                    *(float4*)(op + 4) = *(float4*)&o8[4];
                } else {
                    *(float4*)op = *(float4*)&o8[0];
                }
            }
        }
    }
}

extern "C" void kernel_launch(void* const* d_in, const int* in_sizes, int n_in,
                              void* d_out, int out_size, void* d_ws, size_t ws_size,
                              hipStream_t stream) {
    const float* x     = (const float*)d_in[0];
    const int*   ei    = (const int*)d_in[1];
    const float* W1l   = (const float*)d_in[2];
    const float* b1l   = (const float*)d_in[3];
    const float* W1r   = (const float*)d_in[4];
    const float* b1r   = (const float*)d_in[5];
    const float* att1  = (const float*)d_in[6];
    const float* bias1 = (const float*)d_in[7];
    const float* W2l   = (const float*)d_in[8];
    const float* b2l   = (const float*)d_in[9];
    const float* W2r   = (const float*)d_in[10];
    const float* b2r   = (const float*)d_in[11];
    const float* att2  = (const float*)d_in[12];
    const float* bias2 = (const float*)d_in[13];
    float* out = (float*)d_out;

    int N     = in_sizes[0] / F_IN;   // 100000
    int Eorig = in_sizes[1] / 2;      // 1600000
    int Etot  = Eorig + N;
    int BK    = (N + NBKT - 1) / NBKT;   // 782 buckets (<=1024)

    char* p = (char*)d_ws;
    auto alloc = [&](size_t bytes) { void* r = (void*)p; p += (bytes + 255) & ~(size_t)255; return r; };
    unsigned short* xl1h = (unsigned short*)alloc((size_t)N * HID * 2);   // f16 table L1
    unsigned short* xr1h = (unsigned short*)alloc((size_t)N * HID * 2);   // f16 xr L1
    unsigned short* h    = (unsigned short*)alloc((size_t)N * HID * 2);   // f16 layer-1 out
    unsigned short* xl2h = (unsigned short*)alloc((size_t)N * NCLS * 2);  // f16 table L2
    unsigned short* xr2h = (unsigned short*)alloc((size_t)N * NCLS * 2);  // f16 xr L2
    int*   cnt     = (int*)alloc((size_t)N * 4);
    int*   rowstart= (int*)alloc((size_t)N * 4);
    int*   srclist = (int*)alloc((size_t)Etot * 4);
    uint4* wfrag   = (uint4*)alloc(2048 * 16);   // frag-ordered bf16 W1
    float* sl1     = (float*)alloc((size_t)N * 4);   // 0.6*att1.xl1 per node
    float* sl2     = (float*)alloc((size_t)N * 4);   // 0.6*att2.xl2 per node
    unsigned short* att1h = (unsigned short*)alloc(HID * 2);
    unsigned short* att2h = (unsigned short*)alloc(NCLS * 2);
    int*   bucketSize   = (int*)alloc(1040 * 4);
    int*   bucketStart  = (int*)alloc(1040 * 4);
    int*   bucketCursor = (int*)alloc(1040 * 4);
    // packed pairs (6.8MB) aliased over h (12.8MB f16, dead during CSR build)
    int*   pairs   = (int*)h;

    int nChunks = (Etot + CHUNK - 1) / CHUNK;      // 416

    // ---- CSR build (prepW overlapped with hist; scatter/t1 separate: R10 lesson) ----
    hipMemsetAsync(bucketSize, 0, 1040 * 4, stream);
    histPrep<<<nChunks + 9, 256, 0, stream>>>(ei, Eorig, Etot, bucketSize, BK, nChunks,
                                              W1l, W1r, att1, att2, wfrag, att1h, att2h);
    bucketScan<<<1, 256, 0, stream>>>(bucketSize, bucketStart, bucketCursor, BK, Etot);
    bucketScatter<<<nChunks, 256, 0, stream>>>(ei, Eorig, Etot, bucketCursor, pairs, BK);
    bucketCSR<<<BK, 256, 0, stream>>>(pairs, bucketStart, rowstart, cnt, srclist, N);

    // ---- layer 1 ----
    transform1<<<(N + 63) / 64, 256, 0, stream>>>(x, wfrag, b1l, b1r, att1, xl1h, xr1h, sl1, N);
    fusedAggG<HID, true><<<(N + 7) / 8, 256, 0, stream>>>(xl1h, xr1h, att1h, sl1, rowstart, cnt,
                                                          srclist, bias1, h, N);

    // ---- layer 2 ----
    transform2<<<(N + 127) / 128, 256, 0, stream>>>(h, W2l, b2l, W2r, b2r, att2, xl2h, xr2h, sl2, N);
    fusedAggG<NCLS, false><<<(N + 7) / 8, 256, 0, stream>>>(xl2h, xr2h, att2h, sl2, rowstart, cnt,
                                                            srclist, bias2, out, N);
}